// Round 3
// baseline (1546.779 us; speedup 1.0000x reference)
//
#include <hip/hip_runtime.h>
#include <hip/hip_bf16.h>

// Problem constants (B=2, L=2048, D=1024, DI=2048, N=16, DCONV=4, DTR=64, I=4096)
// Dtype findings:
//  - Round 1: inputs are fp32 (bf16 reinterpretation of fp32 bits -> NaN). Confirmed.
//  - Round 2: outputs are ALSO fp32. Error 7.18 == max|residual2| + max|out0| -- the
//    signature of bf16-packed outputs being reinterpreted as fp32 (odd elements kept,
//    out1 region read as out0's second half). The "(bf16, ...)" in the test label is
//    hardcoded text, not the output read dtype.
#define BB 2
#define LL 2048
#define DD 1024
#define DI_ 2048
#define NS 16
#define DTR_ 64
#define XDW 96           // DTR + 2N
#define BLR 4096         // B*L rows
#define NC 16            // scan chunks
#define CLEN 128         // chunk length (NC*CLEN == LL)

typedef __attribute__((ext_vector_type(8))) short s16x8;
typedef __attribute__((ext_vector_type(4))) float f32x4;

__device__ __forceinline__ float bfraw2f(unsigned short u){
  union { unsigned int i; float f; } x; x.i = ((unsigned int)u) << 16; return x.f;
}
__device__ __forceinline__ unsigned short f2bfraw(float f){
  union { float f; unsigned int i; } x; x.f = f;
  unsigned int u = x.i;
  u += 0x7FFFu + ((u >> 16) & 1u);   // RNE
  return (unsigned short)(u >> 16);
}
__device__ __forceinline__ short f2bf_rna(float f){   // round-nearest-ties-away (cheap, for weights)
  union { float f; unsigned int i; } x; x.f = f;
  return (short)((x.i + 0x8000u) >> 16);
}
__device__ __forceinline__ float silu_(float a){ return a / (1.f + expf(-a)); }
__device__ __forceinline__ float softplus_(float v){ return v > 20.f ? v : log1pf(expf(v)); }

// ---------------- fused add + LayerNorm (row per block, D=1024, 256 thr x 4) ----------------
// Inputs fp32; emits h (bf16), optional fp32 copy of (pa+pb).
__global__ __launch_bounds__(256) void k_add_ln(
  const float* __restrict__ pa, const float* __restrict__ pb,
  const float* __restrict__ w, const float* __restrict__ bi,
  float* __restrict__ res_f,
  unsigned short* __restrict__ h_out)
{
  int row = blockIdx.x, tid = threadIdx.x;
  int lane = tid & 63, wave = tid >> 6;
  int c0 = tid * 4;
  size_t base = (size_t)row * DD + c0;
  float v[4];
  f32x4 av = *(const f32x4*)(pa + base);
  f32x4 bv = *(const f32x4*)(pb + base);
  #pragma unroll
  for (int k=0;k<4;k++) v[k] = av[k] + bv[k];
  float s_ = v[0]+v[1]+v[2]+v[3];
  #pragma unroll
  for (int off=32; off>0; off>>=1) s_ += __shfl_down(s_, off, 64);
  __shared__ float red1[4], red2[4];
  if (lane==0) red1[wave] = s_;
  __syncthreads();
  float mean = (red1[0]+red1[1]+red1[2]+red1[3]) * (1.f/DD);
  float ss = 0.f;
  #pragma unroll
  for (int k=0;k<4;k++){ float dv = v[k]-mean; ss += dv*dv; }
  #pragma unroll
  for (int off=32; off>0; off>>=1) ss += __shfl_down(ss, off, 64);
  if (lane==0) red2[wave] = ss;
  __syncthreads();
  float var = (red2[0]+red2[1]+red2[2]+red2[3]) * (1.f/DD);
  float rs = rsqrtf(var + 1e-5f);
  f32x4 wv = *(const f32x4*)(w + c0);
  f32x4 biv = *(const f32x4*)(bi + c0);
  unsigned long long hv = 0;
  #pragma unroll
  for (int k=0;k<4;k++){
    float hn = (v[k]-mean)*rs*wv[k] + biv[k];
    hv |= ((unsigned long long)(unsigned short)f2bfraw(hn)) << (16*k);
  }
  *(unsigned long long*)(h_out + base) = hv;
  if (res_f){ f32x4 o = {v[0],v[1],v[2],v[3]}; *(f32x4*)(res_f + base) = o; }
}

// ---------------- generic MFMA GEMM: C[M,N] = A[M,K] * W[N,K]^T ----------------
// A is internal bf16 (lda elements/row). W is an INPUT weight in fp32, converted
// to bf16 in-register at fragment-load time. 128x128 block tile, 4 waves (2x2),
// each wave 4x4 fragments of 16x16x32 bf16 MFMA, direct-global fragment loads.
// EPI: 0 = plain store, 1 = softplus(v + bias[col]). Batched via blockIdx.z.
template<int EPI>
__global__ __launch_bounds__(256) void k_gemm_bt(
  const unsigned short* __restrict__ A0, const unsigned short* __restrict__ A1,
  const float* __restrict__ W0, const float* __restrict__ W1,
  float* __restrict__ Cf0, float* __restrict__ Cf1,
  unsigned short* __restrict__ Cb0, unsigned short* __restrict__ Cb1,
  const float* __restrict__ bias0, const float* __restrict__ bias1,
  int M, int N, int K, int lda)
{
  const unsigned short* A = blockIdx.z ? A1 : A0;
  const float* W = blockIdx.z ? W1 : W0;
  float* Cf = blockIdx.z ? Cf1 : Cf0;
  unsigned short* Cb = blockIdx.z ? Cb1 : Cb0;
  const float* bias = blockIdx.z ? bias1 : bias0;

  int tid = threadIdx.x;
  int wave = tid >> 6, lane = tid & 63;
  int l16 = lane & 15, quad = lane >> 4;
  int m_base = blockIdx.y*128 + (wave>>1)*64;
  int n_base = blockIdx.x*128 + (wave&1)*64;

  f32x4 acc[4][4] = {};
  int kc = quad*8;
  const unsigned short* Arow[4];
  const float* Wrow[4];
  #pragma unroll
  for (int i=0;i<4;i++){ int r = m_base + i*16 + l16; if (r >= M) r = M-1; Arow[i] = A + (size_t)r*lda + kc; }
  #pragma unroll
  for (int j=0;j<4;j++){ int r = n_base + j*16 + l16; if (r >= N) r = N-1; Wrow[j] = W + (size_t)r*K + kc; }

  for (int k0 = 0; k0 < K; k0 += 32){
    s16x8 af[4], bw[4];
    #pragma unroll
    for (int i=0;i<4;i++) af[i] = *(const s16x8*)(Arow[i] + k0);
    #pragma unroll
    for (int j=0;j<4;j++){
      f32x4 lo = *(const f32x4*)(Wrow[j] + k0);
      f32x4 hi = *(const f32x4*)(Wrow[j] + k0 + 4);
      s16x8 t;
      #pragma unroll
      for (int e=0;e<4;e++){ t[e] = f2bf_rna(lo[e]); t[4+e] = f2bf_rna(hi[e]); }
      bw[j] = t;
    }
    #pragma unroll
    for (int i=0;i<4;i++)
      #pragma unroll
      for (int j=0;j<4;j++)
        acc[i][j] = __builtin_amdgcn_mfma_f32_16x16x32_bf16(af[i], bw[j], acc[i][j], 0, 0, 0);
  }

  // C/D layout (m89-verified): col = lane&15, row = quad*4 + reg
  #pragma unroll
  for (int j=0;j<4;j++){
    int col = n_base + j*16 + l16;
    if (col >= N) continue;
    float bval = (EPI==1) ? bias[col] : 0.f;
    #pragma unroll
    for (int i=0;i<4;i++){
      #pragma unroll
      for (int r=0;r<4;r++){
        int rowi = m_base + i*16 + quad*4 + r;
        if (rowi >= M) continue;
        float v = acc[i][j][r];
        if (EPI==1) v = softplus_(v + bval);
        size_t off = (size_t)rowi*N + col;
        if (Cf) Cf[off] = v;
        if (Cb) Cb[off] = f2bfraw(v);
      }
    }
  }
}

// ---------------- causal (dir 0) / anti-causal (dir 1) depthwise conv + SiLU ----------------
// Reads x = xz[:, 0:DI] (bf16 internal); weights fp32 inputs.
// dir 1 output is stored in reversed-local time.
__global__ __launch_bounds__(256) void k_conv(
  const unsigned short* __restrict__ xz,
  const float* __restrict__ cw0, const float* __restrict__ cb0,
  const float* __restrict__ cw1, const float* __restrict__ cb1,
  unsigned short* __restrict__ xc0, unsigned short* __restrict__ xc1)
{
  int row = blockIdx.x;            // b*L + t (direction-local output time)
  int dir = blockIdx.y;
  int b = row >> 11, t = row & (LL-1);
  int d0 = threadIdx.x * 8;
  const float* cw = dir ? cw1 : cw0;
  const float* cb = dir ? cb1 : cb0;
  unsigned short* xc = dir ? xc1 : xc0;

  float acc[8];
  #pragma unroll
  for (int ii=0;ii<8;ii++) acc[ii] = cb[d0+ii];
  float wv[8][4];
  #pragma unroll
  for (int ii=0;ii<8;ii++)
    #pragma unroll
    for (int k=0;k<4;k++) wv[ii][k] = cw[(d0+ii)*4 + k];

  #pragma unroll
  for (int k=0;k<4;k++){
    int j = t - 3 + k;
    if (j < 0) continue;
    int in_row = dir ? (LL-1-j) : j;
    union { s16x8 v; unsigned short e[8]; } xu;
    xu.v = *(const s16x8*)(xz + ((size_t)(b*LL + in_row))*4096 + d0);
    #pragma unroll
    for (int ii=0;ii<8;ii++) acc[ii] += wv[ii][k] * bfraw2f(xu.e[ii]);
  }
  union { s16x8 v; unsigned short e[8]; } ou;
  #pragma unroll
  for (int ii=0;ii<8;ii++) ou.e[ii] = f2bfraw(silu_(acc[ii]));
  *(s16x8*)(xc + (size_t)row*DI_ + d0) = ou.v;
}

// ---------------- chunked selective scan ----------------
// Pass 1: per chunk, with s0=0: accumulate local state and P = prod(dA). Both dirs in one launch.
__global__ __launch_bounds__(256) void k_scan1(
  const unsigned short* __restrict__ xc0, const unsigned short* __restrict__ xc1,
  const unsigned short* __restrict__ dt0, const unsigned short* __restrict__ dt1,
  const float* __restrict__ xd0, const float* __restrict__ xd1,
  const float* __restrict__ al0, const float* __restrict__ al1,
  float* __restrict__ cP, float* __restrict__ cS)
{
  int dir = blockIdx.z >> 1, b = blockIdx.z & 1;
  int c = blockIdx.y;
  int d = blockIdx.x*256 + threadIdx.x;
  const unsigned short* xc = dir ? xc1 : xc0;
  const unsigned short* dt = dir ? dt1 : dt0;
  const float* xd = dir ? xd1 : xd0;
  const float* al = dir ? al1 : al0;

  __shared__ float bc[CLEN*32];
  size_t rb = ((size_t)(b*LL + c*CLEN))*XDW + DTR_;
  for (int idx = threadIdx.x; idx < CLEN*32; idx += 256){
    int tl = idx >> 5, col = idx & 31;
    bc[idx] = xd[rb + (size_t)tl*XDW + col];
  }
  __syncthreads();

  float a2[NS], s[NS], P[NS];
  #pragma unroll
  for (int n=0;n<NS;n++){
    a2[n] = -expf(al[d*NS+n]) * 1.44269504f;  // A * log2(e)
    s[n] = 0.f; P[n] = 1.f;
  }
  size_t rowb = (size_t)(b*LL + c*CLEN)*DI_ + d;
  for (int tl=0; tl<CLEN; tl++){
    float dtv = bfraw2f(dt[rowb]);
    float xv  = bfraw2f(xc[rowb]);
    rowb += DI_;
    float dtx = dtv*xv;
    const float* bcp = &bc[tl*32];
    #pragma unroll
    for (int n=0;n<NS;n++){
      float da = exp2f(dtv*a2[n]);
      s[n] = s[n]*da + dtx*bcp[n];
      P[n] *= da;
    }
  }
  size_t ob = ((size_t)((dir*2+b)*NC + c)*DI_ + d)*NS;
  #pragma unroll
  for (int q=0;q<4;q++){
    f32x4 tp = {P[q*4],P[q*4+1],P[q*4+2],P[q*4+3]};
    f32x4 ts = {s[q*4],s[q*4+1],s[q*4+2],s[q*4+3]};
    *(f32x4*)(cP+ob+q*4) = tp;
    *(f32x4*)(cS+ob+q*4) = ts;
  }
}

// Pass 2: sequential chunk combine: s0[c] = s_end[c-1] + P[c-1]*s0[c-1]
__global__ __launch_bounds__(256) void k_scan2(
  const float* __restrict__ cP, const float* __restrict__ cS, float* __restrict__ cS0)
{
  int gid = blockIdx.x*256 + threadIdx.x;   // 2*2*2048*16 = 131072
  int n = gid & 15;
  int d = (gid >> 4) & 2047;
  int db = gid >> 15;                       // dir*2 + b
  const size_t cstride = (size_t)DI_*NS;
  size_t base = (size_t)db*NC*cstride + (size_t)d*NS + n;
  float cur = 0.f;
  cS0[base] = 0.f;
  for (int c=1;c<NC;c++){
    size_t prev = base + (size_t)(c-1)*cstride;
    cur = cS[prev] + cP[prev]*cur;
    cS0[base + (size_t)c*cstride] = cur;
  }
}

// Pass 3: replay chunk with true initial state, emit y + x*Dp into y_sum.
// dir 0 stores; dir 1 (launched after) adds at reversed positions.
__global__ __launch_bounds__(256) void k_scan3(
  const unsigned short* __restrict__ xc, const unsigned short* __restrict__ dt,
  const float* __restrict__ xd, const float* __restrict__ al,
  const float* __restrict__ Dp, const float* __restrict__ cS0,
  float* __restrict__ y_sum, int dir)
{
  int b = blockIdx.z;
  int c = blockIdx.y;
  int d = blockIdx.x*256 + threadIdx.x;

  __shared__ float bc[CLEN*32];
  size_t rb = ((size_t)(b*LL + c*CLEN))*XDW + DTR_;
  for (int idx = threadIdx.x; idx < CLEN*32; idx += 256){
    int tl = idx >> 5, col = idx & 31;
    bc[idx] = xd[rb + (size_t)tl*XDW + col];
  }
  __syncthreads();

  float a2[NS], s[NS];
  size_t sb = ((size_t)((dir*2+b)*NC + c)*DI_ + d)*NS;
  #pragma unroll
  for (int n=0;n<NS;n++){
    a2[n] = -expf(al[d*NS+n]) * 1.44269504f;
    s[n] = cS0[sb + n];
  }
  float Dd = Dp[d];
  size_t rowb = (size_t)(b*LL + c*CLEN)*DI_ + d;
  for (int tl=0; tl<CLEN; tl++){
    float dtv = bfraw2f(dt[rowb]);
    float xv  = bfraw2f(xc[rowb]);
    float dtx = dtv*xv;
    const float* bcp = &bc[tl*32];
    float y = 0.f;
    #pragma unroll
    for (int n=0;n<NS;n++){
      float da = exp2f(dtv*a2[n]);
      s[n] = s[n]*da + dtx*bcp[n];
      y += s[n]*bcp[16+n];
    }
    float val = y + xv*Dd;
    int t = c*CLEN + tl;
    if (dir == 0){
      y_sum[rowb] = val;
    } else {
      size_t p = (size_t)(b*LL + (LL-1-t))*DI_ + d;
      y_sum[p] += val;
    }
    rowb += DI_;
  }
}

// ---------------- y_sum * silu(z) -> bf16 ----------------
__global__ __launch_bounds__(256) void k_combine(
  const float* __restrict__ y, const unsigned short* __restrict__ xz,
  unsigned short* __restrict__ o)
{
  size_t i = ((size_t)blockIdx.x*256 + threadIdx.x)*4;
  size_t row = i >> 11;
  int d = (int)(i & 2047);
  f32x4 yv = *(const f32x4*)(y + i);
  unsigned long long zv = *(const unsigned long long*)(xz + row*4096 + 2048 + d);
  unsigned long long ov = 0;
  #pragma unroll
  for (int k=0;k<4;k++){
    float z = bfraw2f((unsigned short)(zv >> (16*k)));
    ov |= ((unsigned long long)(unsigned short)f2bfraw(yv[k]*silu_(z))) << (16*k);
  }
  *(unsigned long long*)(o + i) = ov;
}

// ---------------- silu(gate)*up -> bf16 ----------------
__global__ __launch_bounds__(256) void k_silu_mul(
  const unsigned short* __restrict__ g, const unsigned short* __restrict__ u,
  unsigned short* __restrict__ o)
{
  size_t i = ((size_t)blockIdx.x*256 + threadIdx.x)*8;
  union { s16x8 v; unsigned short e[8]; } gv, uv, ov;
  gv.v = *(const s16x8*)(g+i);
  uv.v = *(const s16x8*)(u+i);
  #pragma unroll
  for (int k=0;k<8;k++){
    float a = bfraw2f(gv.e[k]);
    ov.e[k] = f2bfraw(silu_(a) * bfraw2f(uv.e[k]));
  }
  *(s16x8*)(o+i) = ov.v;
}

extern "C" void kernel_launch(void* const* d_in, const int* in_sizes, int n_in,
                              void* d_out, int out_size, void* d_ws, size_t ws_size,
                              hipStream_t stream)
{
  typedef const float* cfp;
  cfp hs = (cfp)d_in[0], res = (cfp)d_in[1], inproj = (cfp)d_in[2], outproj = (cfp)d_in[3];
  cfp conv_w_f=(cfp)d_in[4],  conv_b_f=(cfp)d_in[5],  xproj_f=(cfp)d_in[6],  dtw_f=(cfp)d_in[7],
      dtb_f=(cfp)d_in[8],     alog_f=(cfp)d_in[9],    Dp_f=(cfp)d_in[10];
  cfp conv_w_r=(cfp)d_in[11], conv_b_r=(cfp)d_in[12], xproj_r=(cfp)d_in[13], dtw_r=(cfp)d_in[14],
      dtb_r=(cfp)d_in[15],    alog_r=(cfp)d_in[16],   Dp_r=(cfp)d_in[17];
  cfp ln1w=(cfp)d_in[18], ln1b=(cfp)d_in[19], ln2w=(cfp)d_in[20], ln2b=(cfp)d_in[21];
  cfp gw=(cfp)d_in[22], uw=(cfp)d_in[23], dwn=(cfp)d_in[24];

  // Workspace layout (206,045,184 bytes peak; later phases reuse dead scan buffers)
  char* ws = (char*)d_ws;
  float*          res1    = (float*)(ws + 0);                    // 16.78 MB, fp32 residual chain
  unsigned short* xz      = (unsigned short*)(ws + 16777216);    // 33.55 MB (BLR x 4096 bf16)
  unsigned short* xcf     = (unsigned short*)(ws + 50331648);    // conv+silu out, fwd
  unsigned short* xcr     = (unsigned short*)(ws + 67108864);    // conv+silu out, rev (reversed time)
  float*          xdf     = (float*)(ws + 83886080);             // x_dbl f32, fwd (BLR x 96)
  float*          xdr     = (float*)(ws + 85458944);
  unsigned short* xdbf    = (unsigned short*)(ws + 87031808);    // x_dbl bf16, fwd
  unsigned short* xdbr    = (unsigned short*)(ws + 87818240);
  unsigned short* dtf     = (unsigned short*)(ws + 88604672);    // softplus(dt) bf16, fwd
  unsigned short* dtr     = (unsigned short*)(ws + 105381888);
  float*          cP      = (float*)(ws + 122159104);            // chunk prod(dA)
  float*          cS      = (float*)(ws + 130547712);            // chunk local end-state
  float*          cS0     = (float*)(ws + 138936320);            // chunk initial state
  float*          ysum    = (float*)(ws + 147324928);            // fp32 y_f + y_r
  unsigned short* ysum_bf = (unsigned short*)(ws + 180879360);
  unsigned short* h_bf    = (unsigned short*)(ws + 197656576);   // LN out (h, then h2)
  // reuse (dead by the time they're written):
  float*          mm_out  = (float*)(ws + 122159104);            // over cP+cS (dead after scan2)
  unsigned short* gate_bf = (unsigned short*)(ws + 147324928);   // over ysum (dead after combine)
  unsigned short* up_bf   = (unsigned short*)(ws + 88604672);    // over dtf+dtr (dead after scan3)
  unsigned short* act_bf  = (unsigned short*)(ws + 16777216);    // over xz (dead after combine)
  float* out0f = (float*)d_out;                                  // MLP out (B,L,D) fp32
  float* out1f = out0f + 4194304;                                // residual2 (B,L,D) fp32

  // 1. res1 = hs + residual; h = LN1(res1)
  k_add_ln<<<BLR, 256, 0, stream>>>(hs, res, ln1w, ln1b, res1, h_bf);
  // 2. xz = h @ inproj^T  (M=4096, N=4096, K=1024)
  k_gemm_bt<0><<<dim3(32,32,1),256,0,stream>>>(h_bf,h_bf, inproj,inproj,
      nullptr,nullptr, xz,xz, nullptr,nullptr, BLR, 4096, 1024, 1024);
  // 3. depthwise conv + silu, both directions
  k_conv<<<dim3(BLR,2),256,0,stream>>>(xz, conv_w_f, conv_b_f, conv_w_r, conv_b_r, xcf, xcr);
  // 4. x_dbl = xc @ xproj^T  (N=96, K=2048), both dirs batched
  k_gemm_bt<0><<<dim3(1,32,2),256,0,stream>>>(xcf,xcr, xproj_f,xproj_r,
      xdf,xdr, xdbf,xdbr, nullptr,nullptr, BLR, XDW, 2048, 2048);
  // 5. dt = softplus(x_dbl[:, :64] @ dtproj^T + b)  (N=2048, K=64, lda=96)
  k_gemm_bt<1><<<dim3(16,32,2),256,0,stream>>>(xdbf,xdbr, dtw_f,dtw_r,
      nullptr,nullptr, dtf,dtr, dtb_f,dtb_r, BLR, DI_, DTR_, XDW);
  // 6-8. chunked scan
  k_scan1<<<dim3(8,NC,4),256,0,stream>>>(xcf,xcr, dtf,dtr, xdf,xdr, alog_f,alog_r, cP, cS);
  k_scan2<<<512,256,0,stream>>>(cP, cS, cS0);
  k_scan3<<<dim3(8,NC,2),256,0,stream>>>(xcf, dtf, xdf, alog_f, Dp_f, cS0, ysum, 0);
  k_scan3<<<dim3(8,NC,2),256,0,stream>>>(xcr, dtr, xdr, alog_r, Dp_r, cS0, ysum, 1);
  // 9. ysum_bf = (y_f + y_r) * silu(z)
  k_combine<<<8192,256,0,stream>>>(ysum, xz, ysum_bf);
  // 10. mm_out = ysum_bf @ outproj^T  (N=1024, K=2048) — (out_f+out_r) folded into one GEMM
  k_gemm_bt<0><<<dim3(8,32,1),256,0,stream>>>(ysum_bf,ysum_bf, outproj,outproj,
      mm_out,mm_out, nullptr,nullptr, nullptr,nullptr, BLR, DD, 2048, 2048);
  // 11. residual2 = mm_out + res1 -> out1 (fp32); h2 = LN2(residual2)
  k_add_ln<<<BLR, 256, 0, stream>>>(mm_out, res1, ln2w, ln2b, out1f, h_bf);
  // 12. gate/up GEMMs batched (N=4096, K=1024)
  k_gemm_bt<0><<<dim3(32,32,2),256,0,stream>>>(h_bf,h_bf, gw,uw,
      nullptr,nullptr, gate_bf,up_bf, nullptr,nullptr, BLR, 4096, 1024, 1024);
  // 13. act = silu(gate)*up
  k_silu_mul<<<8192,256,0,stream>>>(gate_bf, up_bf, act_bf);
  // 14. out0 = act @ down^T  (N=1024, K=4096), fp32 store
  k_gemm_bt<0><<<dim3(8,32,1),256,0,stream>>>(act_bf,act_bf, dwn,dwn,
      out0f,out0f, nullptr,nullptr, nullptr,nullptr, BLR, DD, 4096, 4096);
}

// Round 4
// 1051.615 us; speedup vs baseline: 1.4709x; 1.4709x over previous
//
#include <hip/hip_runtime.h>
#include <hip/hip_bf16.h>

// Problem constants (B=2, L=2048, D=1024, DI=2048, N=16, DCONV=4, DTR=64, I=4096)
// Dtype findings (R1/R2): inputs fp32, outputs fp32 (out0=mlp_out, out1=residual2).
// R3: passed, 1547 us. GEMMs latency-bound (MfmaUtil 7.5%) -> this round: m97-style
// LDS-staged MFMA GEMM (global_load_lds width=16) + one-shot fp32->bf16 weight cache.
#define BB 2
#define LL 2048
#define DD 1024
#define DI_ 2048
#define NS 16
#define DTR_ 64
#define XDW 96           // DTR + 2N
#define BLR 4096         // B*L rows
#define NC 16            // scan chunks
#define CLEN 128         // chunk length (NC*CLEN == LL)

typedef __attribute__((ext_vector_type(8))) short s16x8;
typedef __attribute__((ext_vector_type(4))) float f32x4;

__device__ __forceinline__ float bfraw2f(unsigned short u){
  union { unsigned int i; float f; } x; x.i = ((unsigned int)u) << 16; return x.f;
}
__device__ __forceinline__ unsigned short f2bfraw(float f){
  union { float f; unsigned int i; } x; x.f = f;
  unsigned int u = x.i;
  u += 0x7FFFu + ((u >> 16) & 1u);   // RNE
  return (unsigned short)(u >> 16);
}
__device__ __forceinline__ float silu_(float a){ return a / (1.f + expf(-a)); }
__device__ __forceinline__ float softplus_(float v){ return v > 20.f ? v : log1pf(expf(v)); }

// async global->LDS, 16B per lane. LDS dest = wave-uniform base + lane*16 (m104).
typedef __attribute__((address_space(1))) void gas_void;
typedef __attribute__((address_space(3))) void las_void;
__device__ __forceinline__ void gl_lds16(const unsigned short* g, unsigned short* l){
  __builtin_amdgcn_global_load_lds((gas_void*)g, (las_void*)l, 16, 0, 0);
}

// ---------------- weight fp32 -> bf16 cache (9 segments, one launch) ----------------
struct CvtArgs {
  const float* s[9];
  unsigned short* d;
  unsigned int off[10];   // element offsets into d (and within concatenation)
};
__global__ __launch_bounds__(256) void k_wcvt(CvtArgs a, unsigned int total4){
  unsigned int g = blockIdx.x*256 + threadIdx.x;
  if (g >= total4) return;
  unsigned int e = g*4;
  int sgi = 0;
  #pragma unroll
  for (int i=1;i<9;i++) if (e >= a.off[i]) sgi = i;
  const float* s = a.s[sgi];
  f32x4 v = *(const f32x4*)(s + (e - a.off[sgi]));
  unsigned long long o = 0;
  #pragma unroll
  for (int k=0;k<4;k++) o |= ((unsigned long long)f2bfraw(v[k])) << (16*k);
  *(unsigned long long*)(a.d + e) = o;
}

// ---------------- fused add + LayerNorm (row per block, D=1024, 256 thr x 4) ----------------
__global__ __launch_bounds__(256) void k_add_ln(
  const float* __restrict__ pa, const float* __restrict__ pb,
  const float* __restrict__ w, const float* __restrict__ bi,
  float* __restrict__ res_f,
  unsigned short* __restrict__ h_out)
{
  int row = blockIdx.x, tid = threadIdx.x;
  int lane = tid & 63, wave = tid >> 6;
  int c0 = tid * 4;
  size_t base = (size_t)row * DD + c0;
  float v[4];
  f32x4 av = *(const f32x4*)(pa + base);
  f32x4 bv = *(const f32x4*)(pb + base);
  #pragma unroll
  for (int k=0;k<4;k++) v[k] = av[k] + bv[k];
  float s_ = v[0]+v[1]+v[2]+v[3];
  #pragma unroll
  for (int off=32; off>0; off>>=1) s_ += __shfl_down(s_, off, 64);
  __shared__ float red1[4], red2[4];
  if (lane==0) red1[wave] = s_;
  __syncthreads();
  float mean = (red1[0]+red1[1]+red1[2]+red1[3]) * (1.f/DD);
  float ss = 0.f;
  #pragma unroll
  for (int k=0;k<4;k++){ float dv = v[k]-mean; ss += dv*dv; }
  #pragma unroll
  for (int off=32; off>0; off>>=1) ss += __shfl_down(ss, off, 64);
  if (lane==0) red2[wave] = ss;
  __syncthreads();
  float var = (red2[0]+red2[1]+red2[2]+red2[3]) * (1.f/DD);
  float rs = rsqrtf(var + 1e-5f);
  f32x4 wv = *(const f32x4*)(w + c0);
  f32x4 biv = *(const f32x4*)(bi + c0);
  unsigned long long hv = 0;
  #pragma unroll
  for (int k=0;k<4;k++){
    float hn = (v[k]-mean)*rs*wv[k] + biv[k];
    hv |= ((unsigned long long)(unsigned short)f2bfraw(hn)) << (16*k);
  }
  *(unsigned long long*)(h_out + base) = hv;
  if (res_f){ f32x4 o = {v[0],v[1],v[2],v[3]}; *(f32x4*)(res_f + base) = o; }
}

// ---------------- m97-style LDS-staged MFMA GEMM: C[M,N] = A[M,K] * W[N,K]^T ----------------
// A, W both bf16. 128x128 block tile, BK=64, 4 waves (2x2), wave = 4x4 frags of
// 16x16x32 bf16 MFMA. Staging: global_load_lds dwordx4, 8 per thread per K-iter
// (A 16KB + B 16KB). 2-barrier K-loop. EPI: 0 = plain, 1 = softplus(v+bias[col]).
// Batched via blockIdx.z (two pointer sets). Requires K%64==0, M%128==0.
template<int EPI>
__global__ __launch_bounds__(256) void k_gemm_lds(
  const unsigned short* __restrict__ A0, const unsigned short* __restrict__ A1,
  const unsigned short* __restrict__ W0, const unsigned short* __restrict__ W1,
  float* __restrict__ Cf0, float* __restrict__ Cf1,
  unsigned short* __restrict__ Cb0, unsigned short* __restrict__ Cb1,
  const float* __restrict__ bias0, const float* __restrict__ bias1,
  int M, int N, int K, int lda)
{
  __shared__ unsigned short Asm[128*64];
  __shared__ unsigned short Bsm[128*64];
  const unsigned short* A = blockIdx.z ? A1 : A0;
  const unsigned short* W = blockIdx.z ? W1 : W0;
  float* Cf = blockIdx.z ? Cf1 : Cf0;
  unsigned short* Cb = blockIdx.z ? Cb1 : Cb0;
  const float* bias = blockIdx.z ? bias1 : bias0;

  int tid = threadIdx.x;
  int wave = tid >> 6, lane = tid & 63;
  int l16 = lane & 15, quad = lane >> 4;
  int wm = (wave >> 1) * 64, wn = (wave & 1) * 64;
  int m0 = blockIdx.y * 128, n0 = blockIdx.x * 128;

  // Staging map: 16 chunks of 1KB; chunk ca=(wave*4+c) covers tile rows ca*8+(lane>>3),
  // cols (lane&7)*8 .. +8. LDS lane-order layout == row-major [row][k] (no padding!).
  const unsigned short* ag[4];
  const unsigned short* wg[4];
  unsigned short* al[4];
  unsigned short* bl[4];
  #pragma unroll
  for (int c = 0; c < 4; c++){
    int ca = wave*4 + c;
    int ra = m0 + ca*8 + (lane>>3); if (ra >= M) ra = M-1;
    int rb = n0 + ca*8 + (lane>>3); if (rb >= N) rb = N-1;
    int col = (lane&7)*8;
    ag[c] = A + (size_t)ra*lda + col;
    wg[c] = W + (size_t)rb*K + col;
    al[c] = Asm + ca*512;     // wave-uniform LDS base per chunk
    bl[c] = Bsm + ca*512;
  }

  f32x4 acc[4][4] = {};

  for (int k0 = 0; k0 < K; k0 += 64){
    #pragma unroll
    for (int c = 0; c < 4; c++){
      gl_lds16(ag[c] + k0, al[c]);
      gl_lds16(wg[c] + k0, bl[c]);
    }
    __syncthreads();             // drains vmcnt(0): staged data visible
    #pragma unroll
    for (int s = 0; s < 2; s++){
      s16x8 af[4], bw[4];
      #pragma unroll
      for (int i = 0; i < 4; i++)
        af[i] = *(const s16x8*)(Asm + (wm + i*16 + l16)*64 + s*32 + quad*8);
      #pragma unroll
      for (int j = 0; j < 4; j++)
        bw[j] = *(const s16x8*)(Bsm + (wn + j*16 + l16)*64 + s*32 + quad*8);
      #pragma unroll
      for (int i = 0; i < 4; i++)
        #pragma unroll
        for (int j = 0; j < 4; j++)
          acc[i][j] = __builtin_amdgcn_mfma_f32_16x16x32_bf16(af[i], bw[j], acc[i][j], 0, 0, 0);
    }
    __syncthreads();             // protect LDS from next-iter staging
  }

  // C/D layout (m89-verified): col = lane&15, row = quad*4 + reg
  #pragma unroll
  for (int j=0;j<4;j++){
    int col = n0 + wn + j*16 + l16;
    if (col >= N) continue;
    float bval = (EPI==1) ? bias[col] : 0.f;
    #pragma unroll
    for (int i=0;i<4;i++){
      #pragma unroll
      for (int r=0;r<4;r++){
        int rowi = m0 + wm + i*16 + quad*4 + r;
        float v = acc[i][j][r];
        if (EPI==1) v = softplus_(v + bval);
        size_t off = (size_t)rowi*N + col;
        if (Cf) Cf[off] = v;
        if (Cb) Cb[off] = f2bfraw(v);
      }
    }
  }
}

// ---------------- causal (dir 0) / anti-causal (dir 1) depthwise conv + SiLU ----------------
__global__ __launch_bounds__(256) void k_conv(
  const unsigned short* __restrict__ xz,
  const float* __restrict__ cw0, const float* __restrict__ cb0,
  const float* __restrict__ cw1, const float* __restrict__ cb1,
  unsigned short* __restrict__ xc0, unsigned short* __restrict__ xc1)
{
  int row = blockIdx.x;            // b*L + t (direction-local output time)
  int dir = blockIdx.y;
  int b = row >> 11, t = row & (LL-1);
  int d0 = threadIdx.x * 8;
  const float* cw = dir ? cw1 : cw0;
  const float* cb = dir ? cb1 : cb0;
  unsigned short* xc = dir ? xc1 : xc0;

  float acc[8];
  #pragma unroll
  for (int ii=0;ii<8;ii++) acc[ii] = cb[d0+ii];
  float wv[8][4];
  #pragma unroll
  for (int ii=0;ii<8;ii++)
    #pragma unroll
    for (int k=0;k<4;k++) wv[ii][k] = cw[(d0+ii)*4 + k];

  #pragma unroll
  for (int k=0;k<4;k++){
    int j = t - 3 + k;
    if (j < 0) continue;
    int in_row = dir ? (LL-1-j) : j;
    union { s16x8 v; unsigned short e[8]; } xu;
    xu.v = *(const s16x8*)(xz + ((size_t)(b*LL + in_row))*4096 + d0);
    #pragma unroll
    for (int ii=0;ii<8;ii++) acc[ii] += wv[ii][k] * bfraw2f(xu.e[ii]);
  }
  union { s16x8 v; unsigned short e[8]; } ou;
  #pragma unroll
  for (int ii=0;ii<8;ii++) ou.e[ii] = f2bfraw(silu_(acc[ii]));
  *(s16x8*)(xc + (size_t)row*DI_ + d0) = ou.v;
}

// ---------------- chunked selective scan ----------------
__global__ __launch_bounds__(256) void k_scan1(
  const unsigned short* __restrict__ xc0, const unsigned short* __restrict__ xc1,
  const unsigned short* __restrict__ dt0, const unsigned short* __restrict__ dt1,
  const float* __restrict__ xd0, const float* __restrict__ xd1,
  const float* __restrict__ al0, const float* __restrict__ al1,
  float* __restrict__ cP, float* __restrict__ cS)
{
  int dir = blockIdx.z >> 1, b = blockIdx.z & 1;
  int c = blockIdx.y;
  int d = blockIdx.x*256 + threadIdx.x;
  const unsigned short* xc = dir ? xc1 : xc0;
  const unsigned short* dt = dir ? dt1 : dt0;
  const float* xd = dir ? xd1 : xd0;
  const float* al = dir ? al1 : al0;

  __shared__ float bc[CLEN*32];
  size_t rb = ((size_t)(b*LL + c*CLEN))*XDW + DTR_;
  for (int idx = threadIdx.x; idx < CLEN*32; idx += 256){
    int tl = idx >> 5, col = idx & 31;
    bc[idx] = xd[rb + (size_t)tl*XDW + col];
  }
  __syncthreads();

  float a2[NS], s[NS], P[NS];
  #pragma unroll
  for (int n=0;n<NS;n++){
    a2[n] = -expf(al[d*NS+n]) * 1.44269504f;  // A * log2(e)
    s[n] = 0.f; P[n] = 1.f;
  }
  size_t rowb = (size_t)(b*LL + c*CLEN)*DI_ + d;
  for (int tl=0; tl<CLEN; tl++){
    float dtv = bfraw2f(dt[rowb]);
    float xv  = bfraw2f(xc[rowb]);
    rowb += DI_;
    float dtx = dtv*xv;
    const float* bcp = &bc[tl*32];
    #pragma unroll
    for (int n=0;n<NS;n++){
      float da = exp2f(dtv*a2[n]);
      s[n] = s[n]*da + dtx*bcp[n];
      P[n] *= da;
    }
  }
  size_t ob = ((size_t)((dir*2+b)*NC + c)*DI_ + d)*NS;
  #pragma unroll
  for (int q=0;q<4;q++){
    f32x4 tp = {P[q*4],P[q*4+1],P[q*4+2],P[q*4+3]};
    f32x4 ts = {s[q*4],s[q*4+1],s[q*4+2],s[q*4+3]};
    *(f32x4*)(cP+ob+q*4) = tp;
    *(f32x4*)(cS+ob+q*4) = ts;
  }
}

__global__ __launch_bounds__(256) void k_scan2(
  const float* __restrict__ cP, const float* __restrict__ cS, float* __restrict__ cS0)
{
  int gid = blockIdx.x*256 + threadIdx.x;   // 2*2*2048*16 = 131072
  int n = gid & 15;
  int d = (gid >> 4) & 2047;
  int db = gid >> 15;                       // dir*2 + b
  const size_t cstride = (size_t)DI_*NS;
  size_t base = (size_t)db*NC*cstride + (size_t)d*NS + n;
  float cur = 0.f;
  cS0[base] = 0.f;
  for (int c=1;c<NC;c++){
    size_t prev = base + (size_t)(c-1)*cstride;
    cur = cS[prev] + cP[prev]*cur;
    cS0[base + (size_t)c*cstride] = cur;
  }
}

__global__ __launch_bounds__(256) void k_scan3(
  const unsigned short* __restrict__ xc, const unsigned short* __restrict__ dt,
  const float* __restrict__ xd, const float* __restrict__ al,
  const float* __restrict__ Dp, const float* __restrict__ cS0,
  float* __restrict__ y_sum, int dir)
{
  int b = blockIdx.z;
  int c = blockIdx.y;
  int d = blockIdx.x*256 + threadIdx.x;

  __shared__ float bc[CLEN*32];
  size_t rb = ((size_t)(b*LL + c*CLEN))*XDW + DTR_;
  for (int idx = threadIdx.x; idx < CLEN*32; idx += 256){
    int tl = idx >> 5, col = idx & 31;
    bc[idx] = xd[rb + (size_t)tl*XDW + col];
  }
  __syncthreads();

  float a2[NS], s[NS];
  size_t sb = ((size_t)((dir*2+b)*NC + c)*DI_ + d)*NS;
  #pragma unroll
  for (int n=0;n<NS;n++){
    a2[n] = -expf(al[d*NS+n]) * 1.44269504f;
    s[n] = cS0[sb + n];
  }
  float Dd = Dp[d];
  size_t rowb = (size_t)(b*LL + c*CLEN)*DI_ + d;
  for (int tl=0; tl<CLEN; tl++){
    float dtv = bfraw2f(dt[rowb]);
    float xv  = bfraw2f(xc[rowb]);
    float dtx = dtv*xv;
    const float* bcp = &bc[tl*32];
    float y = 0.f;
    #pragma unroll
    for (int n=0;n<NS;n++){
      float da = exp2f(dtv*a2[n]);
      s[n] = s[n]*da + dtx*bcp[n];
      y += s[n]*bcp[16+n];
    }
    float val = y + xv*Dd;
    int t = c*CLEN + tl;
    if (dir == 0){
      y_sum[rowb] = val;
    } else {
      size_t p = (size_t)(b*LL + (LL-1-t))*DI_ + d;
      y_sum[p] += val;
    }
    rowb += DI_;
  }
}

// ---------------- y_sum * silu(z) -> bf16 ----------------
__global__ __launch_bounds__(256) void k_combine(
  const float* __restrict__ y, const unsigned short* __restrict__ xz,
  unsigned short* __restrict__ o)
{
  size_t i = ((size_t)blockIdx.x*256 + threadIdx.x)*4;
  size_t row = i >> 11;
  int d = (int)(i & 2047);
  f32x4 yv = *(const f32x4*)(y + i);
  unsigned long long zv = *(const unsigned long long*)(xz + row*4096 + 2048 + d);
  unsigned long long ov = 0;
  #pragma unroll
  for (int k=0;k<4;k++){
    float z = bfraw2f((unsigned short)(zv >> (16*k)));
    ov |= ((unsigned long long)(unsigned short)f2bfraw(yv[k]*silu_(z))) << (16*k);
  }
  *(unsigned long long*)(o + i) = ov;
}

// ---------------- silu(gate)*up -> bf16 ----------------
__global__ __launch_bounds__(256) void k_silu_mul(
  const unsigned short* __restrict__ g, const unsigned short* __restrict__ u,
  unsigned short* __restrict__ o)
{
  size_t i = ((size_t)blockIdx.x*256 + threadIdx.x)*8;
  union { s16x8 v; unsigned short e[8]; } gv, uv, ov;
  gv.v = *(const s16x8*)(g+i);
  uv.v = *(const s16x8*)(u+i);
  #pragma unroll
  for (int k=0;k<8;k++){
    float a = bfraw2f(gv.e[k]);
    ov.e[k] = f2bfraw(silu_(a) * bfraw2f(uv.e[k]));
  }
  *(s16x8*)(o+i) = ov.v;
}

extern "C" void kernel_launch(void* const* d_in, const int* in_sizes, int n_in,
                              void* d_out, int out_size, void* d_ws, size_t ws_size,
                              hipStream_t stream)
{
  typedef const float* cfp;
  cfp hs = (cfp)d_in[0], res = (cfp)d_in[1], inproj = (cfp)d_in[2], outproj = (cfp)d_in[3];
  cfp conv_w_f=(cfp)d_in[4],  conv_b_f=(cfp)d_in[5],  xproj_f=(cfp)d_in[6],  dtw_f=(cfp)d_in[7],
      dtb_f=(cfp)d_in[8],     alog_f=(cfp)d_in[9],    Dp_f=(cfp)d_in[10];
  cfp conv_w_r=(cfp)d_in[11], conv_b_r=(cfp)d_in[12], xproj_r=(cfp)d_in[13], dtw_r=(cfp)d_in[14],
      dtb_r=(cfp)d_in[15],    alog_r=(cfp)d_in[16],   Dp_r=(cfp)d_in[17];
  cfp ln1w=(cfp)d_in[18], ln1b=(cfp)d_in[19], ln2w=(cfp)d_in[20], ln2b=(cfp)d_in[21];
  cfp gw=(cfp)d_in[22], uw=(cfp)d_in[23], dwn=(cfp)d_in[24];

  // Workspace layout (245.1 MB peak; later phases reuse dead scan buffers)
  char* ws = (char*)d_ws;
  float*          res1    = (float*)(ws + 0);                    // fp32 residual chain
  unsigned short* xz      = (unsigned short*)(ws + 16777216);    // BLR x 4096 bf16
  unsigned short* xcf     = (unsigned short*)(ws + 50331648);    // conv+silu out, fwd
  unsigned short* xcr     = (unsigned short*)(ws + 67108864);    // conv+silu out, rev (reversed time)
  float*          xdf     = (float*)(ws + 83886080);             // x_dbl f32, fwd (BLR x 96)
  float*          xdr     = (float*)(ws + 85458944);
  unsigned short* xdbf    = (unsigned short*)(ws + 87031808);    // x_dbl bf16, fwd
  unsigned short* xdbr    = (unsigned short*)(ws + 87818240);
  unsigned short* dtf     = (unsigned short*)(ws + 88604672);    // softplus(dt) bf16, fwd
  unsigned short* dtr     = (unsigned short*)(ws + 105381888);
  float*          cP      = (float*)(ws + 122159104);            // chunk prod(dA)
  float*          cS      = (float*)(ws + 130547712);            // chunk local end-state
  float*          cS0     = (float*)(ws + 138936320);            // chunk initial state
  float*          ysum    = (float*)(ws + 147324928);            // fp32 y_f + y_r
  unsigned short* ysum_bf = (unsigned short*)(ws + 180879360);
  unsigned short* h_bf    = (unsigned short*)(ws + 197656576);   // LN out (h, then h2)
  unsigned short* wb      = (unsigned short*)(ws + 206045184);   // bf16 weight cache, 39.06 MB
  // reuse (dead by the time they're written):
  float*          mm_out  = (float*)(ws + 122159104);            // over cP+cS (dead after scan2)
  unsigned short* gate_bf = (unsigned short*)(ws + 147324928);   // over ysum (dead after combine)
  unsigned short* up_bf   = (unsigned short*)(ws + 88604672);    // over dtf+dtr (dead after scan3)
  unsigned short* act_bf  = (unsigned short*)(ws + 16777216);    // over xz (dead after combine)
  float* out0f = (float*)d_out;                                  // MLP out (B,L,D) fp32
  float* out1f = out0f + 4194304;                                // residual2 (B,L,D) fp32

  // bf16 weight cache layout (element offsets)
  unsigned short* inprojb = wb + 0;
  unsigned short* outprojb= wb + 4194304;
  unsigned short* xprojbf = wb + 6291456;
  unsigned short* xprojbr = wb + 6488064;
  unsigned short* dtwbf   = wb + 6684672;
  unsigned short* dtwbr   = wb + 6815744;
  unsigned short* gwb     = wb + 6946816;
  unsigned short* uwb     = wb + 11141120;
  unsigned short* dwnb    = wb + 15335424;  // total 19529728 elems

  // 0. weight fp32 -> bf16 (runs every call; ~25 us)
  CvtArgs ca;
  ca.s[0]=inproj; ca.s[1]=outproj; ca.s[2]=xproj_f; ca.s[3]=xproj_r; ca.s[4]=dtw_f;
  ca.s[5]=dtw_r;  ca.s[6]=gw;      ca.s[7]=uw;      ca.s[8]=dwn;
  ca.d = wb;
  unsigned int offs[10] = {0u,4194304u,6291456u,6488064u,6684672u,6815744u,
                           6946816u,11141120u,15335424u,19529728u};
  for (int i=0;i<10;i++) ca.off[i]=offs[i];
  k_wcvt<<<19072, 256, 0, stream>>>(ca, 4882432u);

  // 1. res1 = hs + residual; h = LN1(res1)
  k_add_ln<<<BLR, 256, 0, stream>>>(hs, res, ln1w, ln1b, res1, h_bf);
  // 2. xz = h @ inproj^T  (M=4096, N=4096, K=1024)
  k_gemm_lds<0><<<dim3(32,32,1),256,0,stream>>>(h_bf,h_bf, inprojb,inprojb,
      nullptr,nullptr, xz,xz, nullptr,nullptr, BLR, 4096, 1024, 1024);
  // 3. depthwise conv + silu, both directions
  k_conv<<<dim3(BLR,2),256,0,stream>>>(xz, conv_w_f, conv_b_f, conv_w_r, conv_b_r, xcf, xcr);
  // 4. x_dbl = xc @ xproj^T  (N=96, K=2048), both dirs batched
  k_gemm_lds<0><<<dim3(1,32,2),256,0,stream>>>(xcf,xcr, xprojbf,xprojbr,
      xdf,xdr, xdbf,xdbr, nullptr,nullptr, BLR, XDW, 2048, 2048);
  // 5. dt = softplus(x_dbl[:, :64] @ dtproj^T + b)  (N=2048, K=64, lda=96)
  k_gemm_lds<1><<<dim3(16,32,2),256,0,stream>>>(xdbf,xdbr, dtwbf,dtwbr,
      nullptr,nullptr, dtf,dtr, dtb_f,dtb_r, BLR, DI_, DTR_, XDW);
  // 6-8. chunked scan
  k_scan1<<<dim3(8,NC,4),256,0,stream>>>(xcf,xcr, dtf,dtr, xdf,xdr, alog_f,alog_r, cP, cS);
  k_scan2<<<512,256,0,stream>>>(cP, cS, cS0);
  k_scan3<<<dim3(8,NC,2),256,0,stream>>>(xcf, dtf, xdf, alog_f, Dp_f, cS0, ysum, 0);
  k_scan3<<<dim3(8,NC,2),256,0,stream>>>(xcr, dtr, xdr, alog_r, Dp_r, cS0, ysum, 1);
  // 9. ysum_bf = (y_f + y_r) * silu(z)
  k_combine<<<8192,256,0,stream>>>(ysum, xz, ysum_bf);
  // 10. mm_out = ysum_bf @ outproj^T  (N=1024, K=2048) — (out_f+out_r) folded into one GEMM
  k_gemm_lds<0><<<dim3(8,32,1),256,0,stream>>>(ysum_bf,ysum_bf, outprojb,outprojb,
      mm_out,mm_out, nullptr,nullptr, nullptr,nullptr, BLR, DD, 2048, 2048);
  // 11. residual2 = mm_out + res1 -> out1 (fp32); h2 = LN2(residual2)
  k_add_ln<<<BLR, 256, 0, stream>>>(mm_out, res1, ln2w, ln2b, out1f, h_bf);
  // 12. gate/up GEMMs batched (N=4096, K=1024)
  k_gemm_lds<0><<<dim3(32,32,2),256,0,stream>>>(h_bf,h_bf, gwb,uwb,
      nullptr,nullptr, gate_bf,up_bf, nullptr,nullptr, BLR, 4096, 1024, 1024);
  // 13. act = silu(gate)*up
  k_silu_mul<<<8192,256,0,stream>>>(gate_bf, up_bf, act_bf);
  // 14. out0 = act @ down^T  (N=1024, K=4096), fp32 store
  k_gemm_lds<0><<<dim3(8,32,1),256,0,stream>>>(act_bf,act_bf, dwnb,dwnb,
      out0f,out0f, nullptr,nullptr, nullptr,nullptr, BLR, DD, 4096, 4096);
}

// Round 5
// 1003.705 us; speedup vs baseline: 1.5411x; 1.0477x over previous
//
#include <hip/hip_runtime.h>
#include <hip/hip_bf16.h>

// Problem constants (B=2, L=2048, D=1024, DI=2048, N=16, DCONV=4, DTR=64, I=4096)
// Dtype findings (R1/R2): inputs fp32, outputs fp32 (out0=mlp_out, out1=residual2).
// R3: 1547us, GEMMs latency-bound. R4: LDS staging -> 1052us, but ds_read had
// ~16-way bank conflicts (row stride 128B = 32 banks; SQ_LDS_BANK_CONFLICT=2.5e7).
// R5: XOR-swizzle (logical col ^ (row&7)*8) -> 2 lanes/bank (free, m136); fuse
// combine into scan3-dir1.
#define BB 2
#define LL 2048
#define DD 1024
#define DI_ 2048
#define NS 16
#define DTR_ 64
#define XDW 96           // DTR + 2N
#define BLR 4096         // B*L rows
#define NC 16            // scan chunks
#define CLEN 128         // chunk length (NC*CLEN == LL)

typedef __attribute__((ext_vector_type(8))) short s16x8;
typedef __attribute__((ext_vector_type(4))) float f32x4;

__device__ __forceinline__ float bfraw2f(unsigned short u){
  union { unsigned int i; float f; } x; x.i = ((unsigned int)u) << 16; return x.f;
}
__device__ __forceinline__ unsigned short f2bfraw(float f){
  union { float f; unsigned int i; } x; x.f = f;
  unsigned int u = x.i;
  u += 0x7FFFu + ((u >> 16) & 1u);   // RNE
  return (unsigned short)(u >> 16);
}
__device__ __forceinline__ float silu_(float a){ return a / (1.f + expf(-a)); }
__device__ __forceinline__ float softplus_(float v){ return v > 20.f ? v : log1pf(expf(v)); }

// async global->LDS, 16B per lane. LDS dest = wave-uniform base + lane*16 (m104).
typedef __attribute__((address_space(1))) void gas_void;
typedef __attribute__((address_space(3))) void las_void;
__device__ __forceinline__ void gl_lds16(const unsigned short* g, unsigned short* l){
  __builtin_amdgcn_global_load_lds((gas_void*)g, (las_void*)l, 16, 0, 0);
}

// ---------------- weight fp32 -> bf16 cache (9 segments, one launch) ----------------
struct CvtArgs {
  const float* s[9];
  unsigned short* d;
  unsigned int off[10];   // element offsets into d (and within concatenation)
};
__global__ __launch_bounds__(256) void k_wcvt(CvtArgs a, unsigned int total4){
  unsigned int g = blockIdx.x*256 + threadIdx.x;
  if (g >= total4) return;
  unsigned int e = g*4;
  int sgi = 0;
  #pragma unroll
  for (int i=1;i<9;i++) if (e >= a.off[i]) sgi = i;
  const float* s = a.s[sgi];
  f32x4 v = *(const f32x4*)(s + (e - a.off[sgi]));
  unsigned long long o = 0;
  #pragma unroll
  for (int k=0;k<4;k++) o |= ((unsigned long long)f2bfraw(v[k])) << (16*k);
  *(unsigned long long*)(a.d + e) = o;
}

// ---------------- fused add + LayerNorm (row per block, D=1024, 256 thr x 4) ----------------
__global__ __launch_bounds__(256) void k_add_ln(
  const float* __restrict__ pa, const float* __restrict__ pb,
  const float* __restrict__ w, const float* __restrict__ bi,
  float* __restrict__ res_f,
  unsigned short* __restrict__ h_out)
{
  int row = blockIdx.x, tid = threadIdx.x;
  int lane = tid & 63, wave = tid >> 6;
  int c0 = tid * 4;
  size_t base = (size_t)row * DD + c0;
  float v[4];
  f32x4 av = *(const f32x4*)(pa + base);
  f32x4 bv = *(const f32x4*)(pb + base);
  #pragma unroll
  for (int k=0;k<4;k++) v[k] = av[k] + bv[k];
  float s_ = v[0]+v[1]+v[2]+v[3];
  #pragma unroll
  for (int off=32; off>0; off>>=1) s_ += __shfl_down(s_, off, 64);
  __shared__ float red1[4], red2[4];
  if (lane==0) red1[wave] = s_;
  __syncthreads();
  float mean = (red1[0]+red1[1]+red1[2]+red1[3]) * (1.f/DD);
  float ss = 0.f;
  #pragma unroll
  for (int k=0;k<4;k++){ float dv = v[k]-mean; ss += dv*dv; }
  #pragma unroll
  for (int off=32; off>0; off>>=1) ss += __shfl_down(ss, off, 64);
  if (lane==0) red2[wave] = ss;
  __syncthreads();
  float var = (red2[0]+red2[1]+red2[2]+red2[3]) * (1.f/DD);
  float rs = rsqrtf(var + 1e-5f);
  f32x4 wv = *(const f32x4*)(w + c0);
  f32x4 biv = *(const f32x4*)(bi + c0);
  unsigned long long hv = 0;
  #pragma unroll
  for (int k=0;k<4;k++){
    float hn = (v[k]-mean)*rs*wv[k] + biv[k];
    hv |= ((unsigned long long)(unsigned short)f2bfraw(hn)) << (16*k);
  }
  *(unsigned long long*)(h_out + base) = hv;
  if (res_f){ f32x4 o = {v[0],v[1],v[2],v[3]}; *(f32x4*)(res_f + base) = o; }
}

// ---------------- LDS-staged MFMA GEMM with XOR-swizzle: C[M,N] = A[M,K] * W[N,K]^T --------
// A, W both bf16. 128x128 block tile, BK=64, 4 waves (2x2), wave = 4x4 frags of
// 16x16x32 bf16 MFMA. Staging: global_load_lds dwordx4. Swizzle: LDS physical col p
// of row r holds logical col p ^ ((r&7)*8); staging lane fetches global col
// ((lane&7)^(lane>>3))*8, fragment reads XOR the same term -> 2 lanes/bank (free).
// EPI: 0 = plain, 1 = softplus(v+bias[col]). Batched via blockIdx.z.
template<int EPI>
__global__ __launch_bounds__(256) void k_gemm_lds(
  const unsigned short* __restrict__ A0, const unsigned short* __restrict__ A1,
  const unsigned short* __restrict__ W0, const unsigned short* __restrict__ W1,
  float* __restrict__ Cf0, float* __restrict__ Cf1,
  unsigned short* __restrict__ Cb0, unsigned short* __restrict__ Cb1,
  const float* __restrict__ bias0, const float* __restrict__ bias1,
  int M, int N, int K, int lda)
{
  __shared__ unsigned short Asm[128*64];
  __shared__ unsigned short Bsm[128*64];
  const unsigned short* A = blockIdx.z ? A1 : A0;
  const unsigned short* W = blockIdx.z ? W1 : W0;
  float* Cf = blockIdx.z ? Cf1 : Cf0;
  unsigned short* Cb = blockIdx.z ? Cb1 : Cb0;
  const float* bias = blockIdx.z ? bias1 : bias0;

  int tid = threadIdx.x;
  int wave = tid >> 6, lane = tid & 63;
  int l16 = lane & 15, quad = lane >> 4;
  int wm = (wave >> 1) * 64, wn = (wave & 1) * 64;
  int m0 = blockIdx.y * 128, n0 = blockIdx.x * 128;

  // Staging: 16 chunks of 1KB; chunk ca=(wave*4+c) covers tile rows ca*8+(lane>>3).
  // Source col is XOR-swizzled so LDS[r][p] = global[r][p ^ (r&7)*8].
  int colsw = (((lane & 7) ^ (lane >> 3)) * 8);
  const unsigned short* ag[4];
  const unsigned short* wg[4];
  unsigned short* al[4];
  unsigned short* bl[4];
  #pragma unroll
  for (int c = 0; c < 4; c++){
    int ca = wave*4 + c;
    int ra = m0 + ca*8 + (lane>>3); if (ra >= M) ra = M-1;
    int rb = n0 + ca*8 + (lane>>3); if (rb >= N) rb = N-1;
    ag[c] = A + (size_t)ra*lda + colsw;
    wg[c] = W + (size_t)rb*K + colsw;
    al[c] = Asm + ca*512;     // wave-uniform LDS base per chunk
    bl[c] = Bsm + ca*512;
  }

  int swz = (l16 & 7) * 8;    // fragment-read de-swizzle (row&7 == l16&7 here)
  f32x4 acc[4][4] = {};

  for (int k0 = 0; k0 < K; k0 += 64){
    #pragma unroll
    for (int c = 0; c < 4; c++){
      gl_lds16(ag[c] + k0, al[c]);
      gl_lds16(wg[c] + k0, bl[c]);
    }
    __syncthreads();             // drains vmcnt(0): staged data visible
    #pragma unroll
    for (int s = 0; s < 2; s++){
      int koff = (s*32 + quad*8) ^ swz;
      s16x8 af[4], bw[4];
      #pragma unroll
      for (int i = 0; i < 4; i++)
        af[i] = *(const s16x8*)(Asm + (wm + i*16 + l16)*64 + koff);
      #pragma unroll
      for (int j = 0; j < 4; j++)
        bw[j] = *(const s16x8*)(Bsm + (wn + j*16 + l16)*64 + koff);
      #pragma unroll
      for (int i = 0; i < 4; i++)
        #pragma unroll
        for (int j = 0; j < 4; j++)
          acc[i][j] = __builtin_amdgcn_mfma_f32_16x16x32_bf16(af[i], bw[j], acc[i][j], 0, 0, 0);
    }
    __syncthreads();             // protect LDS from next-iter staging
  }

  // C/D layout (m89-verified): col = lane&15, row = quad*4 + reg
  #pragma unroll
  for (int j=0;j<4;j++){
    int col = n0 + wn + j*16 + l16;
    if (col >= N) continue;
    float bval = (EPI==1) ? bias[col] : 0.f;
    #pragma unroll
    for (int i=0;i<4;i++){
      #pragma unroll
      for (int r=0;r<4;r++){
        int rowi = m0 + wm + i*16 + quad*4 + r;
        float v = acc[i][j][r];
        if (EPI==1) v = softplus_(v + bval);
        size_t off = (size_t)rowi*N + col;
        if (Cf) Cf[off] = v;
        if (Cb) Cb[off] = f2bfraw(v);
      }
    }
  }
}

// ---------------- causal (dir 0) / anti-causal (dir 1) depthwise conv + SiLU ----------------
__global__ __launch_bounds__(256) void k_conv(
  const unsigned short* __restrict__ xz,
  const float* __restrict__ cw0, const float* __restrict__ cb0,
  const float* __restrict__ cw1, const float* __restrict__ cb1,
  unsigned short* __restrict__ xc0, unsigned short* __restrict__ xc1)
{
  int row = blockIdx.x;            // b*L + t (direction-local output time)
  int dir = blockIdx.y;
  int b = row >> 11, t = row & (LL-1);
  int d0 = threadIdx.x * 8;
  const float* cw = dir ? cw1 : cw0;
  const float* cb = dir ? cb1 : cb0;
  unsigned short* xc = dir ? xc1 : xc0;

  float acc[8];
  #pragma unroll
  for (int ii=0;ii<8;ii++) acc[ii] = cb[d0+ii];
  float wv[8][4];
  #pragma unroll
  for (int ii=0;ii<8;ii++)
    #pragma unroll
    for (int k=0;k<4;k++) wv[ii][k] = cw[(d0+ii)*4 + k];

  #pragma unroll
  for (int k=0;k<4;k++){
    int j = t - 3 + k;
    if (j < 0) continue;
    int in_row = dir ? (LL-1-j) : j;
    union { s16x8 v; unsigned short e[8]; } xu;
    xu.v = *(const s16x8*)(xz + ((size_t)(b*LL + in_row))*4096 + d0);
    #pragma unroll
    for (int ii=0;ii<8;ii++) acc[ii] += wv[ii][k] * bfraw2f(xu.e[ii]);
  }
  union { s16x8 v; unsigned short e[8]; } ou;
  #pragma unroll
  for (int ii=0;ii<8;ii++) ou.e[ii] = f2bfraw(silu_(acc[ii]));
  *(s16x8*)(xc + (size_t)row*DI_ + d0) = ou.v;
}

// ---------------- chunked selective scan ----------------
__global__ __launch_bounds__(256) void k_scan1(
  const unsigned short* __restrict__ xc0, const unsigned short* __restrict__ xc1,
  const unsigned short* __restrict__ dt0, const unsigned short* __restrict__ dt1,
  const float* __restrict__ xd0, const float* __restrict__ xd1,
  const float* __restrict__ al0, const float* __restrict__ al1,
  float* __restrict__ cP, float* __restrict__ cS)
{
  int dir = blockIdx.z >> 1, b = blockIdx.z & 1;
  int c = blockIdx.y;
  int d = blockIdx.x*256 + threadIdx.x;
  const unsigned short* xc = dir ? xc1 : xc0;
  const unsigned short* dt = dir ? dt1 : dt0;
  const float* xd = dir ? xd1 : xd0;
  const float* al = dir ? al1 : al0;

  __shared__ float bc[CLEN*32];
  size_t rb = ((size_t)(b*LL + c*CLEN))*XDW + DTR_;
  for (int idx = threadIdx.x; idx < CLEN*32; idx += 256){
    int tl = idx >> 5, col = idx & 31;
    bc[idx] = xd[rb + (size_t)tl*XDW + col];
  }
  __syncthreads();

  float a2[NS], s[NS], P[NS];
  #pragma unroll
  for (int n=0;n<NS;n++){
    a2[n] = -expf(al[d*NS+n]) * 1.44269504f;  // A * log2(e)
    s[n] = 0.f; P[n] = 1.f;
  }
  size_t rowb = (size_t)(b*LL + c*CLEN)*DI_ + d;
  for (int tl=0; tl<CLEN; tl++){
    float dtv = bfraw2f(dt[rowb]);
    float xv  = bfraw2f(xc[rowb]);
    rowb += DI_;
    float dtx = dtv*xv;
    const float* bcp = &bc[tl*32];
    #pragma unroll
    for (int n=0;n<NS;n++){
      float da = exp2f(dtv*a2[n]);
      s[n] = s[n]*da + dtx*bcp[n];
      P[n] *= da;
    }
  }
  size_t ob = ((size_t)((dir*2+b)*NC + c)*DI_ + d)*NS;
  #pragma unroll
  for (int q=0;q<4;q++){
    f32x4 tp = {P[q*4],P[q*4+1],P[q*4+2],P[q*4+3]};
    f32x4 ts = {s[q*4],s[q*4+1],s[q*4+2],s[q*4+3]};
    *(f32x4*)(cP+ob+q*4) = tp;
    *(f32x4*)(cS+ob+q*4) = ts;
  }
}

__global__ __launch_bounds__(256) void k_scan2(
  const float* __restrict__ cP, const float* __restrict__ cS, float* __restrict__ cS0)
{
  int gid = blockIdx.x*256 + threadIdx.x;   // 2*2*2048*16 = 131072
  int n = gid & 15;
  int d = (gid >> 4) & 2047;
  int db = gid >> 15;                       // dir*2 + b
  const size_t cstride = (size_t)DI_*NS;
  size_t base = (size_t)db*NC*cstride + (size_t)d*NS + n;
  float cur = 0.f;
  cS0[base] = 0.f;
  for (int c=1;c<NC;c++){
    size_t prev = base + (size_t)(c-1)*cstride;
    cur = cS[prev] + cP[prev]*cur;
    cS0[base + (size_t)c*cstride] = cur;
  }
}

// Pass 3: replay chunk with true initial state, emit y + x*Dp.
// dir 0: store fp32 into y_sum. dir 1 (launched after): read y_sum at reversed
// position, add, multiply by silu(z) and store bf16 (combine fused here).
__global__ __launch_bounds__(256) void k_scan3(
  const unsigned short* __restrict__ xc, const unsigned short* __restrict__ dt,
  const float* __restrict__ xd, const float* __restrict__ al,
  const float* __restrict__ Dp, const float* __restrict__ cS0,
  float* __restrict__ y_sum, const unsigned short* __restrict__ xz,
  unsigned short* __restrict__ obf, int dir)
{
  int b = blockIdx.z;
  int c = blockIdx.y;
  int d = blockIdx.x*256 + threadIdx.x;

  __shared__ float bc[CLEN*32];
  size_t rb = ((size_t)(b*LL + c*CLEN))*XDW + DTR_;
  for (int idx = threadIdx.x; idx < CLEN*32; idx += 256){
    int tl = idx >> 5, col = idx & 31;
    bc[idx] = xd[rb + (size_t)tl*XDW + col];
  }
  __syncthreads();

  float a2[NS], s[NS];
  size_t sb = ((size_t)((dir*2+b)*NC + c)*DI_ + d)*NS;
  #pragma unroll
  for (int n=0;n<NS;n++){
    a2[n] = -expf(al[d*NS+n]) * 1.44269504f;
    s[n] = cS0[sb + n];
  }
  float Dd = Dp[d];
  size_t rowb = (size_t)(b*LL + c*CLEN)*DI_ + d;
  for (int tl=0; tl<CLEN; tl++){
    float dtv = bfraw2f(dt[rowb]);
    float xv  = bfraw2f(xc[rowb]);
    float dtx = dtv*xv;
    const float* bcp = &bc[tl*32];
    float y = 0.f;
    #pragma unroll
    for (int n=0;n<NS;n++){
      float da = exp2f(dtv*a2[n]);
      s[n] = s[n]*da + dtx*bcp[n];
      y += s[n]*bcp[16+n];
    }
    float val = y + xv*Dd;
    if (dir == 0){
      y_sum[rowb] = val;
    } else {
      int t = c*CLEN + tl;
      size_t prow = (size_t)(b*LL + (LL-1-t));
      size_t p = prow*DI_ + d;
      float total = y_sum[p] + val;
      float z = bfraw2f(xz[prow*4096 + 2048 + d]);
      obf[p] = f2bfraw(total * silu_(z));
    }
    rowb += DI_;
  }
}

// ---------------- silu(gate)*up -> bf16 ----------------
__global__ __launch_bounds__(256) void k_silu_mul(
  const unsigned short* __restrict__ g, const unsigned short* __restrict__ u,
  unsigned short* __restrict__ o)
{
  size_t i = ((size_t)blockIdx.x*256 + threadIdx.x)*8;
  union { s16x8 v; unsigned short e[8]; } gv, uv, ov;
  gv.v = *(const s16x8*)(g+i);
  uv.v = *(const s16x8*)(u+i);
  #pragma unroll
  for (int k=0;k<8;k++){
    float a = bfraw2f(gv.e[k]);
    ov.e[k] = f2bfraw(silu_(a) * bfraw2f(uv.e[k]));
  }
  *(s16x8*)(o+i) = ov.v;
}

extern "C" void kernel_launch(void* const* d_in, const int* in_sizes, int n_in,
                              void* d_out, int out_size, void* d_ws, size_t ws_size,
                              hipStream_t stream)
{
  typedef const float* cfp;
  cfp hs = (cfp)d_in[0], res = (cfp)d_in[1], inproj = (cfp)d_in[2], outproj = (cfp)d_in[3];
  cfp conv_w_f=(cfp)d_in[4],  conv_b_f=(cfp)d_in[5],  xproj_f=(cfp)d_in[6],  dtw_f=(cfp)d_in[7],
      dtb_f=(cfp)d_in[8],     alog_f=(cfp)d_in[9],    Dp_f=(cfp)d_in[10];
  cfp conv_w_r=(cfp)d_in[11], conv_b_r=(cfp)d_in[12], xproj_r=(cfp)d_in[13], dtw_r=(cfp)d_in[14],
      dtb_r=(cfp)d_in[15],    alog_r=(cfp)d_in[16],   Dp_r=(cfp)d_in[17];
  cfp ln1w=(cfp)d_in[18], ln1b=(cfp)d_in[19], ln2w=(cfp)d_in[20], ln2b=(cfp)d_in[21];
  cfp gw=(cfp)d_in[22], uw=(cfp)d_in[23], dwn=(cfp)d_in[24];

  // Workspace layout (245.1 MB peak; later phases reuse dead scan buffers)
  char* ws = (char*)d_ws;
  float*          res1    = (float*)(ws + 0);                    // fp32 residual chain
  unsigned short* xz      = (unsigned short*)(ws + 16777216);    // BLR x 4096 bf16
  unsigned short* xcf     = (unsigned short*)(ws + 50331648);    // conv+silu out, fwd
  unsigned short* xcr     = (unsigned short*)(ws + 67108864);    // conv+silu out, rev (reversed time)
  float*          xdf     = (float*)(ws + 83886080);             // x_dbl f32, fwd (BLR x 96)
  float*          xdr     = (float*)(ws + 85458944);
  unsigned short* xdbf    = (unsigned short*)(ws + 87031808);    // x_dbl bf16, fwd
  unsigned short* xdbr    = (unsigned short*)(ws + 87818240);
  unsigned short* dtf     = (unsigned short*)(ws + 88604672);    // softplus(dt) bf16, fwd
  unsigned short* dtr     = (unsigned short*)(ws + 105381888);
  float*          cP      = (float*)(ws + 122159104);            // chunk prod(dA)
  float*          cS      = (float*)(ws + 130547712);            // chunk local end-state
  float*          cS0     = (float*)(ws + 138936320);            // chunk initial state
  float*          ysum    = (float*)(ws + 147324928);            // fp32 y_f (dir0)
  unsigned short* ysum_bf = (unsigned short*)(ws + 180879360);
  unsigned short* h_bf    = (unsigned short*)(ws + 197656576);   // LN out (h, then h2)
  unsigned short* wb      = (unsigned short*)(ws + 206045184);   // bf16 weight cache, 39.06 MB
  // reuse (dead by the time they're written):
  float*          mm_out  = (float*)(ws + 122159104);            // over cP+cS (dead after scan2)
  unsigned short* gate_bf = (unsigned short*)(ws + 147324928);   // over ysum (dead after scan3-d1)
  unsigned short* up_bf   = (unsigned short*)(ws + 88604672);    // over dtf+dtr (dead after scan3)
  unsigned short* act_bf  = (unsigned short*)(ws + 16777216);    // over xz (dead after scan3-d1)
  float* out0f = (float*)d_out;                                  // MLP out (B,L,D) fp32
  float* out1f = out0f + 4194304;                                // residual2 (B,L,D) fp32

  // bf16 weight cache layout (element offsets)
  unsigned short* inprojb = wb + 0;
  unsigned short* outprojb= wb + 4194304;
  unsigned short* xprojbf = wb + 6291456;
  unsigned short* xprojbr = wb + 6488064;
  unsigned short* dtwbf   = wb + 6684672;
  unsigned short* dtwbr   = wb + 6815744;
  unsigned short* gwb     = wb + 6946816;
  unsigned short* uwb     = wb + 11141120;
  unsigned short* dwnb    = wb + 15335424;  // total 19529728 elems

  // 0. weight fp32 -> bf16 (runs every call; ~25 us)
  CvtArgs ca;
  ca.s[0]=inproj; ca.s[1]=outproj; ca.s[2]=xproj_f; ca.s[3]=xproj_r; ca.s[4]=dtw_f;
  ca.s[5]=dtw_r;  ca.s[6]=gw;      ca.s[7]=uw;      ca.s[8]=dwn;
  ca.d = wb;
  unsigned int offs[10] = {0u,4194304u,6291456u,6488064u,6684672u,6815744u,
                           6946816u,11141120u,15335424u,19529728u};
  for (int i=0;i<10;i++) ca.off[i]=offs[i];
  k_wcvt<<<19072, 256, 0, stream>>>(ca, 4882432u);

  // 1. res1 = hs + residual; h = LN1(res1)
  k_add_ln<<<BLR, 256, 0, stream>>>(hs, res, ln1w, ln1b, res1, h_bf);
  // 2. xz = h @ inproj^T  (M=4096, N=4096, K=1024)
  k_gemm_lds<0><<<dim3(32,32,1),256,0,stream>>>(h_bf,h_bf, inprojb,inprojb,
      nullptr,nullptr, xz,xz, nullptr,nullptr, BLR, 4096, 1024, 1024);
  // 3. depthwise conv + silu, both directions
  k_conv<<<dim3(BLR,2),256,0,stream>>>(xz, conv_w_f, conv_b_f, conv_w_r, conv_b_r, xcf, xcr);
  // 4. x_dbl = xc @ xproj^T  (N=96, K=2048), both dirs batched
  k_gemm_lds<0><<<dim3(1,32,2),256,0,stream>>>(xcf,xcr, xprojbf,xprojbr,
      xdf,xdr, xdbf,xdbr, nullptr,nullptr, BLR, XDW, 2048, 2048);
  // 5. dt = softplus(x_dbl[:, :64] @ dtproj^T + b)  (N=2048, K=64, lda=96)
  k_gemm_lds<1><<<dim3(16,32,2),256,0,stream>>>(xdbf,xdbr, dtwbf,dtwbr,
      nullptr,nullptr, dtf,dtr, dtb_f,dtb_r, BLR, DI_, DTR_, XDW);
  // 6-8. chunked scan; dir1 pass fuses the silu(z) combine -> ysum_bf
  k_scan1<<<dim3(8,NC,4),256,0,stream>>>(xcf,xcr, dtf,dtr, xdf,xdr, alog_f,alog_r, cP, cS);
  k_scan2<<<512,256,0,stream>>>(cP, cS, cS0);
  k_scan3<<<dim3(8,NC,2),256,0,stream>>>(xcf, dtf, xdf, alog_f, Dp_f, cS0, ysum, nullptr, nullptr, 0);
  k_scan3<<<dim3(8,NC,2),256,0,stream>>>(xcr, dtr, xdr, alog_r, Dp_r, cS0, ysum, xz, ysum_bf, 1);
  // 10. mm_out = ysum_bf @ outproj^T  (N=1024, K=2048) — (out_f+out_r) folded into one GEMM
  k_gemm_lds<0><<<dim3(8,32,1),256,0,stream>>>(ysum_bf,ysum_bf, outprojb,outprojb,
      mm_out,mm_out, nullptr,nullptr, nullptr,nullptr, BLR, DD, 2048, 2048);
  // 11. residual2 = mm_out + res1 -> out1 (fp32); h2 = LN2(residual2)
  k_add_ln<<<BLR, 256, 0, stream>>>(mm_out, res1, ln2w, ln2b, out1f, h_bf);
  // 12. gate/up GEMMs batched (N=4096, K=1024)
  k_gemm_lds<0><<<dim3(32,32,2),256,0,stream>>>(h_bf,h_bf, gwb,uwb,
      nullptr,nullptr, gate_bf,up_bf, nullptr,nullptr, BLR, 4096, 1024, 1024);
  // 13. act = silu(gate)*up
  k_silu_mul<<<8192,256,0,stream>>>(gate_bf, up_bf, act_bf);
  // 14. out0 = act @ down^T  (N=1024, K=4096), fp32 store
  k_gemm_lds<0><<<dim3(8,32,1),256,0,stream>>>(act_bf,act_bf, dwnb,dwnb,
      out0f,out0f, nullptr,nullptr, nullptr,nullptr, BLR, DD, 4096, 4096);
}

// Round 6
// 979.171 us; speedup vs baseline: 1.5797x; 1.0251x over previous
//
#include <hip/hip_runtime.h>
#include <hip/hip_bf16.h>

// Problem constants (B=2, L=2048, D=1024, DI=2048, N=16, DCONV=4, DTR=64, I=4096)
// Findings: inputs fp32, outputs fp32 (out0=mlp_out, out1=residual2).
// R3 1547us (GEMM latency-bound) -> R4 LDS staging 1052us (bank conflicts 2.5e7)
// -> R5 XOR swizzle 1004us (conflicts 0; GEMMs off top-5). R5 top = k_scan3 133us,
// occupancy 10.6% (1 wave/SIMD!). R6: NC 16->64 (CLEN 32), both dirs in one z=4
// launch (2048 blocks = 32 waves/CU), cS0 folded into cP in-place, y_r bf16,
// separate combine. Peak ws stays 245,104,640 B.
#define BB 2
#define LL 2048
#define DD 1024
#define DI_ 2048
#define NS 16
#define DTR_ 64
#define XDW 96           // DTR + 2N
#define BLR 4096         // B*L rows
#define NC 64            // scan chunks
#define CLEN 32          // chunk length (NC*CLEN == LL)

typedef __attribute__((ext_vector_type(8))) short s16x8;
typedef __attribute__((ext_vector_type(4))) float f32x4;

__device__ __forceinline__ float bfraw2f(unsigned short u){
  union { unsigned int i; float f; } x; x.i = ((unsigned int)u) << 16; return x.f;
}
__device__ __forceinline__ unsigned short f2bfraw(float f){
  union { float f; unsigned int i; } x; x.f = f;
  unsigned int u = x.i;
  u += 0x7FFFu + ((u >> 16) & 1u);   // RNE
  return (unsigned short)(u >> 16);
}
__device__ __forceinline__ float silu_(float a){ return a / (1.f + expf(-a)); }
__device__ __forceinline__ float softplus_(float v){ return v > 20.f ? v : log1pf(expf(v)); }

// async global->LDS, 16B per lane. LDS dest = wave-uniform base + lane*16 (m104).
typedef __attribute__((address_space(1))) void gas_void;
typedef __attribute__((address_space(3))) void las_void;
__device__ __forceinline__ void gl_lds16(const unsigned short* g, unsigned short* l){
  __builtin_amdgcn_global_load_lds((gas_void*)g, (las_void*)l, 16, 0, 0);
}

// ---------------- weight fp32 -> bf16 cache (9 segments, one launch) ----------------
struct CvtArgs {
  const float* s[9];
  unsigned short* d;
  unsigned int off[10];   // element offsets into d (and within concatenation)
};
__global__ __launch_bounds__(256) void k_wcvt(CvtArgs a, unsigned int total4){
  unsigned int g = blockIdx.x*256 + threadIdx.x;
  if (g >= total4) return;
  unsigned int e = g*4;
  int sgi = 0;
  #pragma unroll
  for (int i=1;i<9;i++) if (e >= a.off[i]) sgi = i;
  const float* s = a.s[sgi];
  f32x4 v = *(const f32x4*)(s + (e - a.off[sgi]));
  unsigned long long o = 0;
  #pragma unroll
  for (int k=0;k<4;k++) o |= ((unsigned long long)f2bfraw(v[k])) << (16*k);
  *(unsigned long long*)(a.d + e) = o;
}

// ---------------- fused add + LayerNorm (row per block, D=1024, 256 thr x 4) ----------------
__global__ __launch_bounds__(256) void k_add_ln(
  const float* __restrict__ pa, const float* __restrict__ pb,
  const float* __restrict__ w, const float* __restrict__ bi,
  float* __restrict__ res_f,
  unsigned short* __restrict__ h_out)
{
  int row = blockIdx.x, tid = threadIdx.x;
  int lane = tid & 63, wave = tid >> 6;
  int c0 = tid * 4;
  size_t base = (size_t)row * DD + c0;
  float v[4];
  f32x4 av = *(const f32x4*)(pa + base);
  f32x4 bv = *(const f32x4*)(pb + base);
  #pragma unroll
  for (int k=0;k<4;k++) v[k] = av[k] + bv[k];
  float s_ = v[0]+v[1]+v[2]+v[3];
  #pragma unroll
  for (int off=32; off>0; off>>=1) s_ += __shfl_down(s_, off, 64);
  __shared__ float red1[4], red2[4];
  if (lane==0) red1[wave] = s_;
  __syncthreads();
  float mean = (red1[0]+red1[1]+red1[2]+red1[3]) * (1.f/DD);
  float ss = 0.f;
  #pragma unroll
  for (int k=0;k<4;k++){ float dv = v[k]-mean; ss += dv*dv; }
  #pragma unroll
  for (int off=32; off>0; off>>=1) ss += __shfl_down(ss, off, 64);
  if (lane==0) red2[wave] = ss;
  __syncthreads();
  float var = (red2[0]+red2[1]+red2[2]+red2[3]) * (1.f/DD);
  float rs = rsqrtf(var + 1e-5f);
  f32x4 wv = *(const f32x4*)(w + c0);
  f32x4 biv = *(const f32x4*)(bi + c0);
  unsigned long long hv = 0;
  #pragma unroll
  for (int k=0;k<4;k++){
    float hn = (v[k]-mean)*rs*wv[k] + biv[k];
    hv |= ((unsigned long long)(unsigned short)f2bfraw(hn)) << (16*k);
  }
  *(unsigned long long*)(h_out + base) = hv;
  if (res_f){ f32x4 o = {v[0],v[1],v[2],v[3]}; *(f32x4*)(res_f + base) = o; }
}

// ---------------- LDS-staged MFMA GEMM with XOR-swizzle: C[M,N] = A[M,K] * W[N,K]^T --------
// A, W both bf16. 128x128 block tile, BK=64, 4 waves (2x2), wave = 4x4 frags of
// 16x16x32 bf16 MFMA. Staging: global_load_lds dwordx4. Swizzle: LDS physical col p
// of row r holds logical col p ^ ((r&7)*8) -> 2 lanes/bank on ds_read_b128 (free).
// EPI: 0 = plain, 1 = softplus(v+bias[col]). Batched via blockIdx.z.
template<int EPI>
__global__ __launch_bounds__(256) void k_gemm_lds(
  const unsigned short* __restrict__ A0, const unsigned short* __restrict__ A1,
  const unsigned short* __restrict__ W0, const unsigned short* __restrict__ W1,
  float* __restrict__ Cf0, float* __restrict__ Cf1,
  unsigned short* __restrict__ Cb0, unsigned short* __restrict__ Cb1,
  const float* __restrict__ bias0, const float* __restrict__ bias1,
  int M, int N, int K, int lda)
{
  __shared__ unsigned short Asm[128*64];
  __shared__ unsigned short Bsm[128*64];
  const unsigned short* A = blockIdx.z ? A1 : A0;
  const unsigned short* W = blockIdx.z ? W1 : W0;
  float* Cf = blockIdx.z ? Cf1 : Cf0;
  unsigned short* Cb = blockIdx.z ? Cb1 : Cb0;
  const float* bias = blockIdx.z ? bias1 : bias0;

  int tid = threadIdx.x;
  int wave = tid >> 6, lane = tid & 63;
  int l16 = lane & 15, quad = lane >> 4;
  int wm = (wave >> 1) * 64, wn = (wave & 1) * 64;
  int m0 = blockIdx.y * 128, n0 = blockIdx.x * 128;

  int colsw = (((lane & 7) ^ (lane >> 3)) * 8);
  const unsigned short* ag[4];
  const unsigned short* wg[4];
  unsigned short* al[4];
  unsigned short* bl[4];
  #pragma unroll
  for (int c = 0; c < 4; c++){
    int ca = wave*4 + c;
    int ra = m0 + ca*8 + (lane>>3); if (ra >= M) ra = M-1;
    int rb = n0 + ca*8 + (lane>>3); if (rb >= N) rb = N-1;
    ag[c] = A + (size_t)ra*lda + colsw;
    wg[c] = W + (size_t)rb*K + colsw;
    al[c] = Asm + ca*512;     // wave-uniform LDS base per chunk
    bl[c] = Bsm + ca*512;
  }

  int swz = (l16 & 7) * 8;    // fragment-read de-swizzle (row&7 == l16&7 here)
  f32x4 acc[4][4] = {};

  for (int k0 = 0; k0 < K; k0 += 64){
    #pragma unroll
    for (int c = 0; c < 4; c++){
      gl_lds16(ag[c] + k0, al[c]);
      gl_lds16(wg[c] + k0, bl[c]);
    }
    __syncthreads();
    #pragma unroll
    for (int s = 0; s < 2; s++){
      int koff = (s*32 + quad*8) ^ swz;
      s16x8 af[4], bw[4];
      #pragma unroll
      for (int i = 0; i < 4; i++)
        af[i] = *(const s16x8*)(Asm + (wm + i*16 + l16)*64 + koff);
      #pragma unroll
      for (int j = 0; j < 4; j++)
        bw[j] = *(const s16x8*)(Bsm + (wn + j*16 + l16)*64 + koff);
      #pragma unroll
      for (int i = 0; i < 4; i++)
        #pragma unroll
        for (int j = 0; j < 4; j++)
          acc[i][j] = __builtin_amdgcn_mfma_f32_16x16x32_bf16(af[i], bw[j], acc[i][j], 0, 0, 0);
    }
    __syncthreads();
  }

  // C/D layout (m89-verified): col = lane&15, row = quad*4 + reg
  #pragma unroll
  for (int j=0;j<4;j++){
    int col = n0 + wn + j*16 + l16;
    if (col >= N) continue;
    float bval = (EPI==1) ? bias[col] : 0.f;
    #pragma unroll
    for (int i=0;i<4;i++){
      #pragma unroll
      for (int r=0;r<4;r++){
        int rowi = m0 + wm + i*16 + quad*4 + r;
        float v = acc[i][j][r];
        if (EPI==1) v = softplus_(v + bval);
        size_t off = (size_t)rowi*N + col;
        if (Cf) Cf[off] = v;
        if (Cb) Cb[off] = f2bfraw(v);
      }
    }
  }
}

// ---------------- causal (dir 0) / anti-causal (dir 1) depthwise conv + SiLU ----------------
__global__ __launch_bounds__(256) void k_conv(
  const unsigned short* __restrict__ xz,
  const float* __restrict__ cw0, const float* __restrict__ cb0,
  const float* __restrict__ cw1, const float* __restrict__ cb1,
  unsigned short* __restrict__ xc0, unsigned short* __restrict__ xc1)
{
  int row = blockIdx.x;            // b*L + t (direction-local output time)
  int dir = blockIdx.y;
  int b = row >> 11, t = row & (LL-1);
  int d0 = threadIdx.x * 8;
  const float* cw = dir ? cw1 : cw0;
  const float* cb = dir ? cb1 : cb0;
  unsigned short* xc = dir ? xc1 : xc0;

  float acc[8];
  #pragma unroll
  for (int ii=0;ii<8;ii++) acc[ii] = cb[d0+ii];
  float wv[8][4];
  #pragma unroll
  for (int ii=0;ii<8;ii++)
    #pragma unroll
    for (int k=0;k<4;k++) wv[ii][k] = cw[(d0+ii)*4 + k];

  #pragma unroll
  for (int k=0;k<4;k++){
    int j = t - 3 + k;
    if (j < 0) continue;
    int in_row = dir ? (LL-1-j) : j;
    union { s16x8 v; unsigned short e[8]; } xu;
    xu.v = *(const s16x8*)(xz + ((size_t)(b*LL + in_row))*4096 + d0);
    #pragma unroll
    for (int ii=0;ii<8;ii++) acc[ii] += wv[ii][k] * bfraw2f(xu.e[ii]);
  }
  union { s16x8 v; unsigned short e[8]; } ou;
  #pragma unroll
  for (int ii=0;ii<8;ii++) ou.e[ii] = f2bfraw(silu_(acc[ii]));
  *(s16x8*)(xc + (size_t)row*DI_ + d0) = ou.v;
}

// ---------------- chunked selective scan (NC=64, CLEN=32) ----------------
// Pass 1: per chunk, s0=0: local end-state cS and P=prod(dA) -> cP. z = dir*2+b.
__global__ __launch_bounds__(256) void k_scan1(
  const unsigned short* __restrict__ xc0, const unsigned short* __restrict__ xc1,
  const unsigned short* __restrict__ dt0, const unsigned short* __restrict__ dt1,
  const float* __restrict__ xd0, const float* __restrict__ xd1,
  const float* __restrict__ al0, const float* __restrict__ al1,
  float* __restrict__ cP, float* __restrict__ cS)
{
  int dir = blockIdx.z >> 1, b = blockIdx.z & 1;
  int c = blockIdx.y;
  int d = blockIdx.x*256 + threadIdx.x;
  const unsigned short* xc = dir ? xc1 : xc0;
  const unsigned short* dt = dir ? dt1 : dt0;
  const float* xd = dir ? xd1 : xd0;
  const float* al = dir ? al1 : al0;

  __shared__ float bc[CLEN*32];
  size_t rb = ((size_t)(b*LL + c*CLEN))*XDW + DTR_;
  for (int idx = threadIdx.x; idx < CLEN*32; idx += 256){
    int tl = idx >> 5, col = idx & 31;
    bc[idx] = xd[rb + (size_t)tl*XDW + col];
  }
  __syncthreads();

  float a2[NS], s[NS], P[NS];
  #pragma unroll
  for (int n=0;n<NS;n++){
    a2[n] = -expf(al[d*NS+n]) * 1.44269504f;  // A * log2(e)
    s[n] = 0.f; P[n] = 1.f;
  }
  size_t rowb = (size_t)(b*LL + c*CLEN)*DI_ + d;
  for (int tl=0; tl<CLEN; tl++){
    float dtv = bfraw2f(dt[rowb]);
    float xv  = bfraw2f(xc[rowb]);
    rowb += DI_;
    float dtx = dtv*xv;
    const float* bcp = &bc[tl*32];
    #pragma unroll
    for (int n=0;n<NS;n++){
      float da = exp2f(dtv*a2[n]);
      s[n] = s[n]*da + dtx*bcp[n];
      P[n] *= da;
    }
  }
  size_t ob = ((size_t)(blockIdx.z*NC + c)*DI_ + d)*NS;
  #pragma unroll
  for (int q=0;q<4;q++){
    f32x4 tp = {P[q*4],P[q*4+1],P[q*4+2],P[q*4+3]};
    f32x4 ts = {s[q*4],s[q*4+1],s[q*4+2],s[q*4+3]};
    *(f32x4*)(cP+ob+q*4) = tp;
    *(f32x4*)(cS+ob+q*4) = ts;
  }
}

// Pass 2: chunk combine. s0 for chunk c is stored IN-PLACE into cP slot (c-1)
// (that slot is never needed again). Chunk 0 has s0=0 (no store).
__global__ __launch_bounds__(256) void k_scan2(
  float* __restrict__ cP, const float* __restrict__ cS)
{
  int gid = blockIdx.x*256 + threadIdx.x;   // 4*2048*16 = 131072
  int n = gid & 15;
  int d = (gid >> 4) & 2047;
  int db = gid >> 15;                       // dir*2 + b
  const size_t cstride = (size_t)DI_*NS;
  size_t base = (size_t)db*NC*cstride + (size_t)d*NS + n;
  float cur = 0.f;
  for (int c=1;c<NC;c++){
    size_t prev = base + (size_t)(c-1)*cstride;
    cur = cS[prev] + cP[prev]*cur;          // read both...
    cP[prev] = cur;                         // ...then clobber (same thread)
  }
}

// Pass 3: replay chunk with true s0 (from cP slot c-1), emit y + x*Dp.
// dir0 -> fp32 y_f; dir1 -> bf16 y_r (dir-local time order). Both dirs one launch.
__global__ __launch_bounds__(256) void k_scan3(
  const unsigned short* __restrict__ xc0, const unsigned short* __restrict__ xc1,
  const unsigned short* __restrict__ dt0, const unsigned short* __restrict__ dt1,
  const float* __restrict__ xd0, const float* __restrict__ xd1,
  const float* __restrict__ al0, const float* __restrict__ al1,
  const float* __restrict__ Dp0, const float* __restrict__ Dp1,
  const float* __restrict__ cP,
  float* __restrict__ y_f, unsigned short* __restrict__ y_r)
{
  int dir = blockIdx.z >> 1, b = blockIdx.z & 1;
  int c = blockIdx.y;
  int d = blockIdx.x*256 + threadIdx.x;
  const unsigned short* xc = dir ? xc1 : xc0;
  const unsigned short* dt = dir ? dt1 : dt0;
  const float* xd = dir ? xd1 : xd0;
  const float* al = dir ? al1 : al0;
  const float* Dp = dir ? Dp1 : Dp0;

  __shared__ float bc[CLEN*32];
  size_t rb = ((size_t)(b*LL + c*CLEN))*XDW + DTR_;
  for (int idx = threadIdx.x; idx < CLEN*32; idx += 256){
    int tl = idx >> 5, col = idx & 31;
    bc[idx] = xd[rb + (size_t)tl*XDW + col];
  }
  __syncthreads();

  float a2[NS], s[NS];
  const size_t cstride = (size_t)DI_*NS;
  size_t sb = (size_t)blockIdx.z*NC*cstride + (size_t)(c-1)*cstride + (size_t)d*NS;
  #pragma unroll
  for (int n=0;n<NS;n++){
    a2[n] = -expf(al[d*NS+n]) * 1.44269504f;
    s[n] = (c == 0) ? 0.f : cP[sb + n];
  }
  float Dd = Dp[d];
  size_t rowb = (size_t)(b*LL + c*CLEN)*DI_ + d;
  for (int tl=0; tl<CLEN; tl++){
    float dtv = bfraw2f(dt[rowb]);
    float xv  = bfraw2f(xc[rowb]);
    float dtx = dtv*xv;
    const float* bcp = &bc[tl*32];
    float y = 0.f;
    #pragma unroll
    for (int n=0;n<NS;n++){
      float da = exp2f(dtv*a2[n]);
      s[n] = s[n]*da + dtx*bcp[n];
      y += s[n]*bcp[16+n];
    }
    float val = y + xv*Dd;
    if (dir == 0) y_f[rowb] = val;
    else          y_r[rowb] = f2bfraw(val);
    rowb += DI_;
  }
}

// ---------------- (y_f[t] + y_r[L-1-t]) * silu(z[t]) -> bf16 ----------------
__global__ __launch_bounds__(256) void k_combine(
  const float* __restrict__ y_f, const unsigned short* __restrict__ y_r,
  const unsigned short* __restrict__ xz, unsigned short* __restrict__ o)
{
  size_t i = ((size_t)blockIdx.x*256 + threadIdx.x)*4;
  size_t row = i >> 11;                 // b*L + t
  int d = (int)(i & 2047);
  int b = (int)(row >> 11), t = (int)(row & (LL-1));
  size_t rrow = (size_t)(b*LL + (LL-1-t));
  f32x4 yv = *(const f32x4*)(y_f + i);
  unsigned long long yrv = *(const unsigned long long*)(y_r + rrow*DI_ + d);
  unsigned long long zv = *(const unsigned long long*)(xz + row*4096 + 2048 + d);
  unsigned long long ov = 0;
  #pragma unroll
  for (int k=0;k<4;k++){
    float tot = yv[k] + bfraw2f((unsigned short)(yrv >> (16*k)));
    float z = bfraw2f((unsigned short)(zv >> (16*k)));
    ov |= ((unsigned long long)(unsigned short)f2bfraw(tot*silu_(z))) << (16*k);
  }
  *(unsigned long long*)(o + i) = ov;
}

// ---------------- silu(gate)*up -> bf16 ----------------
__global__ __launch_bounds__(256) void k_silu_mul(
  const unsigned short* __restrict__ g, const unsigned short* __restrict__ u,
  unsigned short* __restrict__ o)
{
  size_t i = ((size_t)blockIdx.x*256 + threadIdx.x)*8;
  union { s16x8 v; unsigned short e[8]; } gv, uv, ov;
  gv.v = *(const s16x8*)(g+i);
  uv.v = *(const s16x8*)(u+i);
  #pragma unroll
  for (int k=0;k<8;k++){
    float a = bfraw2f(gv.e[k]);
    ov.e[k] = f2bfraw(silu_(a) * bfraw2f(uv.e[k]));
  }
  *(s16x8*)(o+i) = ov.v;
}

extern "C" void kernel_launch(void* const* d_in, const int* in_sizes, int n_in,
                              void* d_out, int out_size, void* d_ws, size_t ws_size,
                              hipStream_t stream)
{
  typedef const float* cfp;
  cfp hs = (cfp)d_in[0], res = (cfp)d_in[1], inproj = (cfp)d_in[2], outproj = (cfp)d_in[3];
  cfp conv_w_f=(cfp)d_in[4],  conv_b_f=(cfp)d_in[5],  xproj_f=(cfp)d_in[6],  dtw_f=(cfp)d_in[7],
      dtb_f=(cfp)d_in[8],     alog_f=(cfp)d_in[9],    Dp_f=(cfp)d_in[10];
  cfp conv_w_r=(cfp)d_in[11], conv_b_r=(cfp)d_in[12], xproj_r=(cfp)d_in[13], dtw_r=(cfp)d_in[14],
      dtb_r=(cfp)d_in[15],    alog_r=(cfp)d_in[16],   Dp_r=(cfp)d_in[17];
  cfp ln1w=(cfp)d_in[18], ln1b=(cfp)d_in[19], ln2w=(cfp)d_in[20], ln2b=(cfp)d_in[21];
  cfp gw=(cfp)d_in[22], uw=(cfp)d_in[23], dwn=(cfp)d_in[24];

  // Workspace layout (peak 245,104,640 B — same as R5)
  char* ws = (char*)d_ws;
  float*          res1    = (float*)(ws + 0);                    // fp32 residual chain (alive to step 11)
  unsigned short* xz      = (unsigned short*)(ws + 16777216);    // BLR x 4096 bf16
  unsigned short* xcf     = (unsigned short*)(ws + 50331648);    // conv+silu out, fwd
  unsigned short* xcr     = (unsigned short*)(ws + 67108864);    // conv+silu out, rev (reversed time)
  float*          xdf     = (float*)(ws + 83886080);             // x_dbl f32, fwd (BLR x 96)
  float*          xdr     = (float*)(ws + 85458944);
  unsigned short* xdbf    = (unsigned short*)(ws + 87031808);    // x_dbl bf16, fwd
  unsigned short* xdbr    = (unsigned short*)(ws + 87818240);
  // time-shared region A [88604672, 105381888): h (step1-2) -> dtf (5-scan3) -> ysum_bf (combine-10) -> h2 (11-12)
  unsigned short* h_bf    = (unsigned short*)(ws + 88604672);
  unsigned short* dtf     = (unsigned short*)(ws + 88604672);
  unsigned short* ysum_bf = (unsigned short*)(ws + 88604672);
  // time-shared region B [105381888, 122159104): dtr (5-scan3) -> mm_out (10-11)
  unsigned short* dtr     = (unsigned short*)(ws + 105381888);
  float*          mm_out  = (float*)(ws + 105381888);
  // scan region [122159104, 222822400): cP, cS (cS reused as ysum_f), ysum_r bf16
  float*          cP      = (float*)(ws + 122159104);            // 33.55 MB; also holds s0 after scan2
  float*          cS      = (float*)(ws + 155713536);            // 33.55 MB
  float*          ysum_f  = (float*)(ws + 155713536);            // over cS (dead after scan2)
  unsigned short* ysum_r  = (unsigned short*)(ws + 189267968);   // 16.77 MB bf16
  unsigned short* wb      = (unsigned short*)(ws + 206045184);   // bf16 weight cache, 39.06 MB (alive all launch)
  // late-phase overlays:
  unsigned short* gate_bf = (unsigned short*)(ws + 122159104);   // over cP (dead after scan3)
  unsigned short* up_bf   = (unsigned short*)(ws + 155713536);   // over ysum_f (dead after combine)
  unsigned short* act_bf  = (unsigned short*)(ws + 16777216);    // over xz (dead after combine)
  float* out0f = (float*)d_out;                                  // MLP out (B,L,D) fp32
  float* out1f = out0f + 4194304;                                // residual2 (B,L,D) fp32

  // bf16 weight cache layout (element offsets)
  unsigned short* inprojb = wb + 0;
  unsigned short* outprojb= wb + 4194304;
  unsigned short* xprojbf = wb + 6291456;
  unsigned short* xprojbr = wb + 6488064;
  unsigned short* dtwbf   = wb + 6684672;
  unsigned short* dtwbr   = wb + 6815744;
  unsigned short* gwb     = wb + 6946816;
  unsigned short* uwb     = wb + 11141120;
  unsigned short* dwnb    = wb + 15335424;  // total 19529728 elems

  // 0. weight fp32 -> bf16 (runs every call; ~20 us)
  CvtArgs ca;
  ca.s[0]=inproj; ca.s[1]=outproj; ca.s[2]=xproj_f; ca.s[3]=xproj_r; ca.s[4]=dtw_f;
  ca.s[5]=dtw_r;  ca.s[6]=gw;      ca.s[7]=uw;      ca.s[8]=dwn;
  ca.d = wb;
  unsigned int offs[10] = {0u,4194304u,6291456u,6488064u,6684672u,6815744u,
                           6946816u,11141120u,15335424u,19529728u};
  for (int i=0;i<10;i++) ca.off[i]=offs[i];
  k_wcvt<<<19072, 256, 0, stream>>>(ca, 4882432u);

  // 1. res1 = hs + residual; h = LN1(res1)
  k_add_ln<<<BLR, 256, 0, stream>>>(hs, res, ln1w, ln1b, res1, h_bf);
  // 2. xz = h @ inproj^T  (M=4096, N=4096, K=1024)
  k_gemm_lds<0><<<dim3(32,32,1),256,0,stream>>>(h_bf,h_bf, inprojb,inprojb,
      nullptr,nullptr, xz,xz, nullptr,nullptr, BLR, 4096, 1024, 1024);
  // 3. depthwise conv + silu, both directions
  k_conv<<<dim3(BLR,2),256,0,stream>>>(xz, conv_w_f, conv_b_f, conv_w_r, conv_b_r, xcf, xcr);
  // 4. x_dbl = xc @ xproj^T  (N=96, K=2048), both dirs batched
  k_gemm_lds<0><<<dim3(1,32,2),256,0,stream>>>(xcf,xcr, xprojbf,xprojbr,
      xdf,xdr, xdbf,xdbr, nullptr,nullptr, BLR, XDW, 2048, 2048);
  // 5. dt = softplus(x_dbl[:, :64] @ dtproj^T + b)  (N=2048, K=64, lda=96)
  k_gemm_lds<1><<<dim3(16,32,2),256,0,stream>>>(xdbf,xdbr, dtwbf,dtwbr,
      nullptr,nullptr, dtf,dtr, dtb_f,dtb_r, BLR, DI_, DTR_, XDW);
  // 6-8. chunked scan (NC=64 chunks of 32; z = dir*2+b, both dirs concurrent)
  k_scan1<<<dim3(8,NC,4),256,0,stream>>>(xcf,xcr, dtf,dtr, xdf,xdr, alog_f,alog_r, cP, cS);
  k_scan2<<<512,256,0,stream>>>(cP, cS);
  k_scan3<<<dim3(8,NC,4),256,0,stream>>>(xcf,xcr, dtf,dtr, xdf,xdr, alog_f,alog_r,
      Dp_f,Dp_r, cP, ysum_f, ysum_r);
  // 9. ysum_bf = (y_f + y_r_reversed) * silu(z)
  k_combine<<<8192,256,0,stream>>>(ysum_f, ysum_r, xz, ysum_bf);
  // 10. mm_out = ysum_bf @ outproj^T  (N=1024, K=2048) — (out_f+out_r) folded into one GEMM
  k_gemm_lds<0><<<dim3(8,32,1),256,0,stream>>>(ysum_bf,ysum_bf, outprojb,outprojb,
      mm_out,mm_out, nullptr,nullptr, nullptr,nullptr, BLR, DD, 2048, 2048);
  // 11. residual2 = mm_out + res1 -> out1 (fp32); h2 = LN2(residual2)
  k_add_ln<<<BLR, 256, 0, stream>>>(mm_out, res1, ln2w, ln2b, out1f, h_bf);
  // 12. gate/up GEMMs batched (N=4096, K=1024)
  k_gemm_lds<0><<<dim3(32,32,2),256,0,stream>>>(h_bf,h_bf, gwb,uwb,
      nullptr,nullptr, gate_bf,up_bf, nullptr,nullptr, BLR, 4096, 1024, 1024);
  // 13. act = silu(gate)*up
  k_silu_mul<<<8192,256,0,stream>>>(gate_bf, up_bf, act_bf);
  // 14. out0 = act @ down^T  (N=1024, K=4096), fp32 store
  k_gemm_lds<0><<<dim3(8,32,1),256,0,stream>>>(act_bf,act_bf, dwnb,dwnb,
      out0f,out0f, nullptr,nullptr, nullptr,nullptr, BLR, DD, 4096, 4096);
}

// Round 7
// 948.277 us; speedup vs baseline: 1.6311x; 1.0326x over previous
//
#include <hip/hip_runtime.h>
#include <hip/hip_bf16.h>

// Problem constants (B=2, L=2048, D=1024, DI=2048, N=16, DCONV=4, DTR=64, I=4096)
// Findings: inputs fp32, outputs fp32 (out0=mlp_out, out1=residual2).
// R3 1547us -> R4 LDS GEMM 1052us -> R5 swizzle 1004us -> R6 scan parallelism 979us.
// R6 counters: top = 200us k_gemm_lds, MfmaUtil 0.4% = x_dbl GEMM with 64 blocks
// (grid 1,32,2) — 75% of CUs idle; plus 2x write amplification (WRITE 68MB vs
// 33.5MB payload) from 2-byte scattered bf16 epilogue stores.
// R7: (1) split-K x_dbl (512 blocks, fp32 atomicAdd + memset); (2) bf16 epilogue
// via LDS transpose -> global_store_dwordx4.
#define BB 2
#define LL 2048
#define DD 1024
#define DI_ 2048
#define NS 16
#define DTR_ 64
#define XDW 96           // DTR + 2N
#define BLR 4096         // B*L rows
#define NC 64            // scan chunks
#define CLEN 32          // chunk length (NC*CLEN == LL)

typedef __attribute__((ext_vector_type(8))) short s16x8;
typedef __attribute__((ext_vector_type(4))) float f32x4;

__device__ __forceinline__ float bfraw2f(unsigned short u){
  union { unsigned int i; float f; } x; x.i = ((unsigned int)u) << 16; return x.f;
}
__device__ __forceinline__ unsigned short f2bfraw(float f){
  union { float f; unsigned int i; } x; x.f = f;
  unsigned int u = x.i;
  u += 0x7FFFu + ((u >> 16) & 1u);   // RNE
  return (unsigned short)(u >> 16);
}
__device__ __forceinline__ float silu_(float a){ return a / (1.f + expf(-a)); }
__device__ __forceinline__ float softplus_(float v){ return v > 20.f ? v : log1pf(expf(v)); }

// async global->LDS, 16B per lane. LDS dest = wave-uniform base + lane*16 (m104).
typedef __attribute__((address_space(1))) void gas_void;
typedef __attribute__((address_space(3))) void las_void;
__device__ __forceinline__ void gl_lds16(const unsigned short* g, unsigned short* l){
  __builtin_amdgcn_global_load_lds((gas_void*)g, (las_void*)l, 16, 0, 0);
}

// ---------------- weight fp32 -> bf16 cache (9 segments, one launch) ----------------
struct CvtArgs {
  const float* s[9];
  unsigned short* d;
  unsigned int off[10];
};
__global__ __launch_bounds__(256) void k_wcvt(CvtArgs a, unsigned int total4){
  unsigned int g = blockIdx.x*256 + threadIdx.x;
  if (g >= total4) return;
  unsigned int e = g*4;
  int sgi = 0;
  #pragma unroll
  for (int i=1;i<9;i++) if (e >= a.off[i]) sgi = i;
  const float* s = a.s[sgi];
  f32x4 v = *(const f32x4*)(s + (e - a.off[sgi]));
  unsigned long long o = 0;
  #pragma unroll
  for (int k=0;k<4;k++) o |= ((unsigned long long)f2bfraw(v[k])) << (16*k);
  *(unsigned long long*)(a.d + e) = o;
}

// ---------------- fused add + LayerNorm (row per block, D=1024, 256 thr x 4) ----------------
__global__ __launch_bounds__(256) void k_add_ln(
  const float* __restrict__ pa, const float* __restrict__ pb,
  const float* __restrict__ w, const float* __restrict__ bi,
  float* __restrict__ res_f,
  unsigned short* __restrict__ h_out)
{
  int row = blockIdx.x, tid = threadIdx.x;
  int lane = tid & 63, wave = tid >> 6;
  int c0 = tid * 4;
  size_t base = (size_t)row * DD + c0;
  float v[4];
  f32x4 av = *(const f32x4*)(pa + base);
  f32x4 bv = *(const f32x4*)(pb + base);
  #pragma unroll
  for (int k=0;k<4;k++) v[k] = av[k] + bv[k];
  float s_ = v[0]+v[1]+v[2]+v[3];
  #pragma unroll
  for (int off=32; off>0; off>>=1) s_ += __shfl_down(s_, off, 64);
  __shared__ float red1[4], red2[4];
  if (lane==0) red1[wave] = s_;
  __syncthreads();
  float mean = (red1[0]+red1[1]+red1[2]+red1[3]) * (1.f/DD);
  float ss = 0.f;
  #pragma unroll
  for (int k=0;k<4;k++){ float dv = v[k]-mean; ss += dv*dv; }
  #pragma unroll
  for (int off=32; off>0; off>>=1) ss += __shfl_down(ss, off, 64);
  if (lane==0) red2[wave] = ss;
  __syncthreads();
  float var = (red2[0]+red2[1]+red2[2]+red2[3]) * (1.f/DD);
  float rs = rsqrtf(var + 1e-5f);
  f32x4 wv = *(const f32x4*)(w + c0);
  f32x4 biv = *(const f32x4*)(bi + c0);
  unsigned long long hv = 0;
  #pragma unroll
  for (int k=0;k<4;k++){
    float hn = (v[k]-mean)*rs*wv[k] + biv[k];
    hv |= ((unsigned long long)(unsigned short)f2bfraw(hn)) << (16*k);
  }
  *(unsigned long long*)(h_out + base) = hv;
  if (res_f){ f32x4 o = {v[0],v[1],v[2],v[3]}; *(f32x4*)(res_f + base) = o; }
}

// ---------------- LDS-staged MFMA GEMM, XOR-swizzle: C[M,N] = A[M,K] * W[N,K]^T ----------
// 128x128 tile, BK=64, 4 waves. bf16 output (Cb) goes through an LDS C-tile
// (row stride 136 bf16: 16B-aligned rows, <=4 lanes/bank) then coalesced
// global_store_dwordx4 (fix for 2x write amplification of scattered 2B stores).
// bf16 path requires M%128==0 && N%128==0 (true for all uses). fp32 path (Cf)
// stores direct (64B/quad, already coalesced). EPI: 0 plain, 1 softplus(v+bias).
template<int EPI>
__global__ __launch_bounds__(256) void k_gemm_lds(
  const unsigned short* __restrict__ A0, const unsigned short* __restrict__ A1,
  const unsigned short* __restrict__ W0, const unsigned short* __restrict__ W1,
  float* __restrict__ Cf0, float* __restrict__ Cf1,
  unsigned short* __restrict__ Cb0, unsigned short* __restrict__ Cb1,
  const float* __restrict__ bias0, const float* __restrict__ bias1,
  int M, int N, int K, int lda)
{
  __shared__ unsigned short S[17408];   // staging: A=S[0:8192), B=S[8192:16384); C-tile: S[0:17408)
  const unsigned short* A = blockIdx.z ? A1 : A0;
  const unsigned short* W = blockIdx.z ? W1 : W0;
  float* Cf = blockIdx.z ? Cf1 : Cf0;
  unsigned short* Cb = blockIdx.z ? Cb1 : Cb0;
  const float* bias = blockIdx.z ? bias1 : bias0;

  int tid = threadIdx.x;
  int wave = tid >> 6, lane = tid & 63;
  int l16 = lane & 15, quad = lane >> 4;
  int wm = (wave >> 1) * 64, wn = (wave & 1) * 64;
  int m0 = blockIdx.y * 128, n0 = blockIdx.x * 128;

  int colsw = (((lane & 7) ^ (lane >> 3)) * 8);
  const unsigned short* ag[4];
  const unsigned short* wg[4];
  unsigned short* al[4];
  unsigned short* bl[4];
  #pragma unroll
  for (int c = 0; c < 4; c++){
    int ca = wave*4 + c;
    int ra = m0 + ca*8 + (lane>>3); if (ra >= M) ra = M-1;
    int rb = n0 + ca*8 + (lane>>3); if (rb >= N) rb = N-1;
    ag[c] = A + (size_t)ra*lda + colsw;
    wg[c] = W + (size_t)rb*K + colsw;
    al[c] = S + ca*512;
    bl[c] = S + 8192 + ca*512;
  }

  int swz = (l16 & 7) * 8;
  f32x4 acc[4][4] = {};

  for (int k0 = 0; k0 < K; k0 += 64){
    #pragma unroll
    for (int c = 0; c < 4; c++){
      gl_lds16(ag[c] + k0, al[c]);
      gl_lds16(wg[c] + k0, bl[c]);
    }
    __syncthreads();
    #pragma unroll
    for (int s = 0; s < 2; s++){
      int koff = (s*32 + quad*8) ^ swz;
      s16x8 af[4], bw[4];
      #pragma unroll
      for (int i = 0; i < 4; i++)
        af[i] = *(const s16x8*)(S + (wm + i*16 + l16)*64 + koff);
      #pragma unroll
      for (int j = 0; j < 4; j++)
        bw[j] = *(const s16x8*)(S + 8192 + (wn + j*16 + l16)*64 + koff);
      #pragma unroll
      for (int i = 0; i < 4; i++)
        #pragma unroll
        for (int j = 0; j < 4; j++)
          acc[i][j] = __builtin_amdgcn_mfma_f32_16x16x32_bf16(af[i], bw[j], acc[i][j], 0, 0, 0);
    }
    __syncthreads();
  }

  // C/D layout (m89-verified): col = lane&15, row = quad*4 + reg
  if (Cb){
    // bf16 path: LDS transpose -> coalesced 16B stores (M,N %128 == 0 guaranteed)
    #pragma unroll
    for (int j=0;j<4;j++){
      int colL = wn + j*16 + l16;
      float bval = (EPI==1) ? bias[n0 + colL] : 0.f;
      #pragma unroll
      for (int i=0;i<4;i++){
        #pragma unroll
        for (int r=0;r<4;r++){
          int rowL = wm + i*16 + quad*4 + r;
          float v = acc[i][j][r];
          if (EPI==1) v = softplus_(v + bval);
          S[rowL*136 + colL] = f2bfraw(v);
        }
      }
    }
    __syncthreads();
    #pragma unroll
    for (int p=0;p<8;p++){
      int e = p*2048 + tid*8;
      int rowL = e >> 7, colL = e & 127;
      s16x8 val = *(const s16x8*)(S + rowL*136 + colL);
      *(s16x8*)(Cb + (size_t)(m0 + rowL)*N + n0 + colL) = val;
    }
  } else {
    #pragma unroll
    for (int j=0;j<4;j++){
      int col = n0 + wn + j*16 + l16;
      if (col >= N) continue;
      float bval = (EPI==1) ? bias[col] : 0.f;
      #pragma unroll
      for (int i=0;i<4;i++){
        #pragma unroll
        for (int r=0;r<4;r++){
          int rowi = m0 + wm + i*16 + quad*4 + r;
          float v = acc[i][j][r];
          if (EPI==1) v = softplus_(v + bval);
          Cf[(size_t)rowi*N + col] = v;
        }
      }
    }
  }
}

// ---------------- split-K GEMM for x_dbl: C[M,96] += A[M,K_seg] * W[96,K_seg]^T ----------
// grid (KSEG=8, M/128, 2 dirs). fp32 atomicAdd into C (memset to 0 beforehand).
// Fixes R6's 64-block under-occupancy (now 512 blocks, 4 K-iters each).
__global__ __launch_bounds__(256) void k_gemm_splitk(
  const unsigned short* __restrict__ A0, const unsigned short* __restrict__ A1,
  const unsigned short* __restrict__ W0, const unsigned short* __restrict__ W1,
  float* __restrict__ C0, float* __restrict__ C1,
  int M, int N, int K, int lda, int kwin)
{
  __shared__ unsigned short S[16384];
  const unsigned short* A = blockIdx.z ? A1 : A0;
  const unsigned short* W = blockIdx.z ? W1 : W0;
  float* C = blockIdx.z ? C1 : C0;

  int tid = threadIdx.x;
  int wave = tid >> 6, lane = tid & 63;
  int l16 = lane & 15, quad = lane >> 4;
  int wm = (wave >> 1) * 64, wn = (wave & 1) * 64;
  int m0 = blockIdx.y * 128;
  int kbase = blockIdx.x * kwin;

  int colsw = (((lane & 7) ^ (lane >> 3)) * 8);
  const unsigned short* ag[4];
  const unsigned short* wg[4];
  unsigned short* al[4];
  unsigned short* bl[4];
  #pragma unroll
  for (int c = 0; c < 4; c++){
    int ca = wave*4 + c;
    int ra = m0 + ca*8 + (lane>>3);
    int rb = ca*8 + (lane>>3); if (rb >= N) rb = N-1;
    ag[c] = A + (size_t)ra*lda + kbase + colsw;
    wg[c] = W + (size_t)rb*K + kbase + colsw;
    al[c] = S + ca*512;
    bl[c] = S + 8192 + ca*512;
  }

  int swz = (l16 & 7) * 8;
  f32x4 acc[4][4] = {};

  for (int k0 = 0; k0 < kwin; k0 += 64){
    #pragma unroll
    for (int c = 0; c < 4; c++){
      gl_lds16(ag[c] + k0, al[c]);
      gl_lds16(wg[c] + k0, bl[c]);
    }
    __syncthreads();
    #pragma unroll
    for (int s = 0; s < 2; s++){
      int koff = (s*32 + quad*8) ^ swz;
      s16x8 af[4], bw[4];
      #pragma unroll
      for (int i = 0; i < 4; i++)
        af[i] = *(const s16x8*)(S + (wm + i*16 + l16)*64 + koff);
      #pragma unroll
      for (int j = 0; j < 4; j++)
        bw[j] = *(const s16x8*)(S + 8192 + (wn + j*16 + l16)*64 + koff);
      #pragma unroll
      for (int i = 0; i < 4; i++)
        #pragma unroll
        for (int j = 0; j < 4; j++)
          acc[i][j] = __builtin_amdgcn_mfma_f32_16x16x32_bf16(af[i], bw[j], acc[i][j], 0, 0, 0);
    }
    __syncthreads();
  }

  #pragma unroll
  for (int j=0;j<4;j++){
    int col = wn + j*16 + l16;
    if (col >= N) continue;
    #pragma unroll
    for (int i=0;i<4;i++){
      #pragma unroll
      for (int r=0;r<4;r++){
        int rowi = m0 + wm + i*16 + quad*4 + r;
        atomicAdd(&C[(size_t)rowi*N + col], acc[i][j][r]);
      }
    }
  }
}

// ---------------- xd fp32 -> bf16 copy (both dirs contiguous) ----------------
__global__ __launch_bounds__(256) void k_xdcvt(
  const float* __restrict__ xd, unsigned short* __restrict__ xdb)
{
  unsigned int e = (blockIdx.x*256 + threadIdx.x)*4;
  f32x4 v = *(const f32x4*)(xd + e);
  unsigned long long o = 0;
  #pragma unroll
  for (int k=0;k<4;k++) o |= ((unsigned long long)f2bfraw(v[k])) << (16*k);
  *(unsigned long long*)(xdb + e) = o;
}

// ---------------- causal (dir 0) / anti-causal (dir 1) depthwise conv + SiLU ----------------
__global__ __launch_bounds__(256) void k_conv(
  const unsigned short* __restrict__ xz,
  const float* __restrict__ cw0, const float* __restrict__ cb0,
  const float* __restrict__ cw1, const float* __restrict__ cb1,
  unsigned short* __restrict__ xc0, unsigned short* __restrict__ xc1)
{
  int row = blockIdx.x;            // b*L + t (direction-local output time)
  int dir = blockIdx.y;
  int b = row >> 11, t = row & (LL-1);
  int d0 = threadIdx.x * 8;
  const float* cw = dir ? cw1 : cw0;
  const float* cb = dir ? cb1 : cb0;
  unsigned short* xc = dir ? xc1 : xc0;

  float acc[8];
  #pragma unroll
  for (int ii=0;ii<8;ii++) acc[ii] = cb[d0+ii];
  float wv[8][4];
  #pragma unroll
  for (int ii=0;ii<8;ii++)
    #pragma unroll
    for (int k=0;k<4;k++) wv[ii][k] = cw[(d0+ii)*4 + k];

  #pragma unroll
  for (int k=0;k<4;k++){
    int j = t - 3 + k;
    if (j < 0) continue;
    int in_row = dir ? (LL-1-j) : j;
    union { s16x8 v; unsigned short e[8]; } xu;
    xu.v = *(const s16x8*)(xz + ((size_t)(b*LL + in_row))*4096 + d0);
    #pragma unroll
    for (int ii=0;ii<8;ii++) acc[ii] += wv[ii][k] * bfraw2f(xu.e[ii]);
  }
  union { s16x8 v; unsigned short e[8]; } ou;
  #pragma unroll
  for (int ii=0;ii<8;ii++) ou.e[ii] = f2bfraw(silu_(acc[ii]));
  *(s16x8*)(xc + (size_t)row*DI_ + d0) = ou.v;
}

// ---------------- chunked selective scan (NC=64, CLEN=32) ----------------
__global__ __launch_bounds__(256) void k_scan1(
  const unsigned short* __restrict__ xc0, const unsigned short* __restrict__ xc1,
  const unsigned short* __restrict__ dt0, const unsigned short* __restrict__ dt1,
  const float* __restrict__ xd0, const float* __restrict__ xd1,
  const float* __restrict__ al0, const float* __restrict__ al1,
  float* __restrict__ cP, float* __restrict__ cS)
{
  int dir = blockIdx.z >> 1, b = blockIdx.z & 1;
  int c = blockIdx.y;
  int d = blockIdx.x*256 + threadIdx.x;
  const unsigned short* xc = dir ? xc1 : xc0;
  const unsigned short* dt = dir ? dt1 : dt0;
  const float* xd = dir ? xd1 : xd0;
  const float* al = dir ? al1 : al0;

  __shared__ float bc[CLEN*32];
  size_t rb = ((size_t)(b*LL + c*CLEN))*XDW + DTR_;
  for (int idx = threadIdx.x; idx < CLEN*32; idx += 256){
    int tl = idx >> 5, col = idx & 31;
    bc[idx] = xd[rb + (size_t)tl*XDW + col];
  }
  __syncthreads();

  float a2[NS], s[NS], P[NS];
  #pragma unroll
  for (int n=0;n<NS;n++){
    a2[n] = -expf(al[d*NS+n]) * 1.44269504f;  // A * log2(e)
    s[n] = 0.f; P[n] = 1.f;
  }
  size_t rowb = (size_t)(b*LL + c*CLEN)*DI_ + d;
  for (int tl=0; tl<CLEN; tl++){
    float dtv = bfraw2f(dt[rowb]);
    float xv  = bfraw2f(xc[rowb]);
    rowb += DI_;
    float dtx = dtv*xv;
    const float* bcp = &bc[tl*32];
    #pragma unroll
    for (int n=0;n<NS;n++){
      float da = exp2f(dtv*a2[n]);
      s[n] = s[n]*da + dtx*bcp[n];
      P[n] *= da;
    }
  }
  size_t ob = ((size_t)(blockIdx.z*NC + c)*DI_ + d)*NS;
  #pragma unroll
  for (int q=0;q<4;q++){
    f32x4 tp = {P[q*4],P[q*4+1],P[q*4+2],P[q*4+3]};
    f32x4 ts = {s[q*4],s[q*4+1],s[q*4+2],s[q*4+3]};
    *(f32x4*)(cP+ob+q*4) = tp;
    *(f32x4*)(cS+ob+q*4) = ts;
  }
}

// Pass 2: chunk combine; s0 for chunk c stored IN-PLACE into cP slot (c-1).
__global__ __launch_bounds__(256) void k_scan2(
  float* __restrict__ cP, const float* __restrict__ cS)
{
  int gid = blockIdx.x*256 + threadIdx.x;   // 4*2048*16 = 131072
  int n = gid & 15;
  int d = (gid >> 4) & 2047;
  int db = gid >> 15;                       // dir*2 + b
  const size_t cstride = (size_t)DI_*NS;
  size_t base = (size_t)db*NC*cstride + (size_t)d*NS + n;
  float cur = 0.f;
  for (int c=1;c<NC;c++){
    size_t prev = base + (size_t)(c-1)*cstride;
    cur = cS[prev] + cP[prev]*cur;
    cP[prev] = cur;
  }
}

// Pass 3: replay chunk with true s0 (cP slot c-1); dir0 -> fp32 y_f, dir1 -> bf16 y_r.
__global__ __launch_bounds__(256) void k_scan3(
  const unsigned short* __restrict__ xc0, const unsigned short* __restrict__ xc1,
  const unsigned short* __restrict__ dt0, const unsigned short* __restrict__ dt1,
  const float* __restrict__ xd0, const float* __restrict__ xd1,
  const float* __restrict__ al0, const float* __restrict__ al1,
  const float* __restrict__ Dp0, const float* __restrict__ Dp1,
  const float* __restrict__ cP,
  float* __restrict__ y_f, unsigned short* __restrict__ y_r)
{
  int dir = blockIdx.z >> 1, b = blockIdx.z & 1;
  int c = blockIdx.y;
  int d = blockIdx.x*256 + threadIdx.x;
  const unsigned short* xc = dir ? xc1 : xc0;
  const unsigned short* dt = dir ? dt1 : dt0;
  const float* xd = dir ? xd1 : xd0;
  const float* al = dir ? al1 : al0;
  const float* Dp = dir ? Dp1 : Dp0;

  __shared__ float bc[CLEN*32];
  size_t rb = ((size_t)(b*LL + c*CLEN))*XDW + DTR_;
  for (int idx = threadIdx.x; idx < CLEN*32; idx += 256){
    int tl = idx >> 5, col = idx & 31;
    bc[idx] = xd[rb + (size_t)tl*XDW + col];
  }
  __syncthreads();

  float a2[NS], s[NS];
  const size_t cstride = (size_t)DI_*NS;
  size_t sb = (size_t)blockIdx.z*NC*cstride + (size_t)(c-1)*cstride + (size_t)d*NS;
  #pragma unroll
  for (int n=0;n<NS;n++){
    a2[n] = -expf(al[d*NS+n]) * 1.44269504f;
    s[n] = (c == 0) ? 0.f : cP[sb + n];
  }
  float Dd = Dp[d];
  size_t rowb = (size_t)(b*LL + c*CLEN)*DI_ + d;
  for (int tl=0; tl<CLEN; tl++){
    float dtv = bfraw2f(dt[rowb]);
    float xv  = bfraw2f(xc[rowb]);
    float dtx = dtv*xv;
    const float* bcp = &bc[tl*32];
    float y = 0.f;
    #pragma unroll
    for (int n=0;n<NS;n++){
      float da = exp2f(dtv*a2[n]);
      s[n] = s[n]*da + dtx*bcp[n];
      y += s[n]*bcp[16+n];
    }
    float val = y + xv*Dd;
    if (dir == 0) y_f[rowb] = val;
    else          y_r[rowb] = f2bfraw(val);
    rowb += DI_;
  }
}

// ---------------- (y_f[t] + y_r[L-1-t]) * silu(z[t]) -> bf16 ----------------
__global__ __launch_bounds__(256) void k_combine(
  const float* __restrict__ y_f, const unsigned short* __restrict__ y_r,
  const unsigned short* __restrict__ xz, unsigned short* __restrict__ o)
{
  size_t i = ((size_t)blockIdx.x*256 + threadIdx.x)*4;
  size_t row = i >> 11;                 // b*L + t
  int d = (int)(i & 2047);
  int b = (int)(row >> 11), t = (int)(row & (LL-1));
  size_t rrow = (size_t)(b*LL + (LL-1-t));
  f32x4 yv = *(const f32x4*)(y_f + i);
  unsigned long long yrv = *(const unsigned long long*)(y_r + rrow*DI_ + d);
  unsigned long long zv = *(const unsigned long long*)(xz + row*4096 + 2048 + d);
  unsigned long long ov = 0;
  #pragma unroll
  for (int k=0;k<4;k++){
    float tot = yv[k] + bfraw2f((unsigned short)(yrv >> (16*k)));
    float z = bfraw2f((unsigned short)(zv >> (16*k)));
    ov |= ((unsigned long long)(unsigned short)f2bfraw(tot*silu_(z))) << (16*k);
  }
  *(unsigned long long*)(o + i) = ov;
}

// ---------------- silu(gate)*up -> bf16 ----------------
__global__ __launch_bounds__(256) void k_silu_mul(
  const unsigned short* __restrict__ g, const unsigned short* __restrict__ u,
  unsigned short* __restrict__ o)
{
  size_t i = ((size_t)blockIdx.x*256 + threadIdx.x)*8;
  union { s16x8 v; unsigned short e[8]; } gv, uv, ov;
  gv.v = *(const s16x8*)(g+i);
  uv.v = *(const s16x8*)(u+i);
  #pragma unroll
  for (int k=0;k<8;k++){
    float a = bfraw2f(gv.e[k]);
    ov.e[k] = f2bfraw(silu_(a) * bfraw2f(uv.e[k]));
  }
  *(s16x8*)(o+i) = ov.v;
}

extern "C" void kernel_launch(void* const* d_in, const int* in_sizes, int n_in,
                              void* d_out, int out_size, void* d_ws, size_t ws_size,
                              hipStream_t stream)
{
  typedef const float* cfp;
  cfp hs = (cfp)d_in[0], res = (cfp)d_in[1], inproj = (cfp)d_in[2], outproj = (cfp)d_in[3];
  cfp conv_w_f=(cfp)d_in[4],  cfp_conv_b_f=(cfp)d_in[5],  xproj_f=(cfp)d_in[6],  dtw_f=(cfp)d_in[7],
      dtb_f=(cfp)d_in[8],     alog_f=(cfp)d_in[9],    Dp_f=(cfp)d_in[10];
  cfp conv_w_r=(cfp)d_in[11], conv_b_r=(cfp)d_in[12], xproj_r=(cfp)d_in[13], dtw_r=(cfp)d_in[14],
      dtb_r=(cfp)d_in[15],    alog_r=(cfp)d_in[16],   Dp_r=(cfp)d_in[17];
  cfp ln1w=(cfp)d_in[18], ln1b=(cfp)d_in[19], ln2w=(cfp)d_in[20], ln2b=(cfp)d_in[21];
  cfp gw=(cfp)d_in[22], uw=(cfp)d_in[23], dwn=(cfp)d_in[24];
  cfp conv_b_f = cfp_conv_b_f;

  // Workspace layout (peak 245,104,640 B)
  char* ws = (char*)d_ws;
  float*          res1    = (float*)(ws + 0);
  unsigned short* xz      = (unsigned short*)(ws + 16777216);
  unsigned short* xcf     = (unsigned short*)(ws + 50331648);
  unsigned short* xcr     = (unsigned short*)(ws + 67108864);
  float*          xdf     = (float*)(ws + 83886080);             // x_dbl f32, fwd (BLR x 96)
  float*          xdr     = (float*)(ws + 85458944);
  unsigned short* xdbf    = (unsigned short*)(ws + 87031808);
  unsigned short* xdbr    = (unsigned short*)(ws + 87818240);
  // time-shared region A: h (1-2) -> dtf (5-scan3) -> ysum_bf (combine-10) -> h2 (11-12)
  unsigned short* h_bf    = (unsigned short*)(ws + 88604672);
  unsigned short* dtf     = (unsigned short*)(ws + 88604672);
  unsigned short* ysum_bf = (unsigned short*)(ws + 88604672);
  // time-shared region B: dtr (5-scan3) -> mm_out (10-11)
  unsigned short* dtr     = (unsigned short*)(ws + 105381888);
  float*          mm_out  = (float*)(ws + 105381888);
  // scan region: cP, cS (cS reused as ysum_f), ysum_r bf16
  float*          cP      = (float*)(ws + 122159104);
  float*          cS      = (float*)(ws + 155713536);
  float*          ysum_f  = (float*)(ws + 155713536);
  unsigned short* ysum_r  = (unsigned short*)(ws + 189267968);
  unsigned short* wb      = (unsigned short*)(ws + 206045184);   // bf16 weight cache
  // late-phase overlays:
  unsigned short* gate_bf = (unsigned short*)(ws + 122159104);
  unsigned short* up_bf   = (unsigned short*)(ws + 155713536);
  unsigned short* act_bf  = (unsigned short*)(ws + 16777216);
  float* out0f = (float*)d_out;
  float* out1f = out0f + 4194304;

  unsigned short* inprojb = wb + 0;
  unsigned short* outprojb= wb + 4194304;
  unsigned short* xprojbf = wb + 6291456;
  unsigned short* xprojbr = wb + 6488064;
  unsigned short* dtwbf   = wb + 6684672;
  unsigned short* dtwbr   = wb + 6815744;
  unsigned short* gwb     = wb + 6946816;
  unsigned short* uwb     = wb + 11141120;
  unsigned short* dwnb    = wb + 15335424;

  // 0. weight fp32 -> bf16; zero xd accumulators (split-K atomic target)
  CvtArgs ca;
  ca.s[0]=inproj; ca.s[1]=outproj; ca.s[2]=xproj_f; ca.s[3]=xproj_r; ca.s[4]=dtw_f;
  ca.s[5]=dtw_r;  ca.s[6]=gw;      ca.s[7]=uw;      ca.s[8]=dwn;
  ca.d = wb;
  unsigned int offs[10] = {0u,4194304u,6291456u,6488064u,6684672u,6815744u,
                           6946816u,11141120u,15335424u,19529728u};
  for (int i=0;i<10;i++) ca.off[i]=offs[i];
  k_wcvt<<<19072, 256, 0, stream>>>(ca, 4882432u);
  hipMemsetAsync(ws + 83886080, 0, 3145728, stream);   // xdf + xdr

  // 1. res1 = hs + residual; h = LN1(res1)
  k_add_ln<<<BLR, 256, 0, stream>>>(hs, res, ln1w, ln1b, res1, h_bf);
  // 2. xz = h @ inproj^T  (M=4096, N=4096, K=1024)
  k_gemm_lds<0><<<dim3(32,32,1),256,0,stream>>>(h_bf,h_bf, inprojb,inprojb,
      nullptr,nullptr, xz,xz, nullptr,nullptr, BLR, 4096, 1024, 1024);
  // 3. depthwise conv + silu, both directions
  k_conv<<<dim3(BLR,2),256,0,stream>>>(xz, conv_w_f, conv_b_f, conv_w_r, conv_b_r, xcf, xcr);
  // 4. x_dbl = xc @ xproj^T  (N=96, K=2048): split-K (8 segs x 32 M-tiles x 2 dirs)
  k_gemm_splitk<<<dim3(8,32,2),256,0,stream>>>(xcf,xcr, xprojbf,xprojbr,
      xdf,xdr, BLR, XDW, 2048, 2048, 256);
  // 4b. bf16 copy of x_dbl (both dirs contiguous)
  k_xdcvt<<<768,256,0,stream>>>(xdf, xdbf);
  // 5. dt = softplus(x_dbl[:, :64] @ dtproj^T + b)  (N=2048, K=64, lda=96)
  k_gemm_lds<1><<<dim3(16,32,2),256,0,stream>>>(xdbf,xdbr, dtwbf,dtwbr,
      nullptr,nullptr, dtf,dtr, dtb_f,dtb_r, BLR, DI_, DTR_, XDW);
  // 6-8. chunked scan (NC=64 chunks of 32; z = dir*2+b)
  k_scan1<<<dim3(8,NC,4),256,0,stream>>>(xcf,xcr, dtf,dtr, xdf,xdr, alog_f,alog_r, cP, cS);
  k_scan2<<<512,256,0,stream>>>(cP, cS);
  k_scan3<<<dim3(8,NC,4),256,0,stream>>>(xcf,xcr, dtf,dtr, xdf,xdr, alog_f,alog_r,
      Dp_f,Dp_r, cP, ysum_f, ysum_r);
  // 9. ysum_bf = (y_f + y_r_reversed) * silu(z)
  k_combine<<<8192,256,0,stream>>>(ysum_f, ysum_r, xz, ysum_bf);
  // 10. mm_out = ysum_bf @ outproj^T  (N=1024, K=2048)
  k_gemm_lds<0><<<dim3(8,32,1),256,0,stream>>>(ysum_bf,ysum_bf, outprojb,outprojb,
      mm_out,mm_out, nullptr,nullptr, nullptr,nullptr, BLR, DD, 2048, 2048);
  // 11. residual2 = mm_out + res1 -> out1 (fp32); h2 = LN2(residual2)
  k_add_ln<<<BLR, 256, 0, stream>>>(mm_out, res1, ln2w, ln2b, out1f, h_bf);
  // 12. gate/up GEMMs batched (N=4096, K=1024)
  k_gemm_lds<0><<<dim3(32,32,2),256,0,stream>>>(h_bf,h_bf, gwb,uwb,
      nullptr,nullptr, gate_bf,up_bf, nullptr,nullptr, BLR, 4096, 1024, 1024);
  // 13. act = silu(gate)*up
  k_silu_mul<<<8192,256,0,stream>>>(gate_bf, up_bf, act_bf);
  // 14. out0 = act @ down^T  (N=1024, K=4096), fp32 store
  k_gemm_lds<0><<<dim3(8,32,1),256,0,stream>>>(act_bf,act_bf, dwnb,dwnb,
      out0f,out0f, nullptr,nullptr, nullptr,nullptr, BLR, DD, 4096, 4096);
}